// Round 7
// baseline (566.868 us; speedup 1.0000x reference)
//
#include <hip/hip_runtime.h>
#include <hip/hip_bf16.h>

typedef __bf16 bf16_t;
typedef __attribute__((ext_vector_type(4))) __bf16 bf16x4;
typedef __attribute__((ext_vector_type(8))) __bf16 bf16x8;
typedef __attribute__((ext_vector_type(4))) float f32x4;

#define NEGV (-1e30f)

// Problem constants
#define BB 4
#define TT 200
#define UU 50
#define U1 51
#define VV 1024
#define DD 512
#define HH 640
#define RTOT (BB*TT*U1)      // 40800
#define RPAD 40832           // 638*64
#define SS 101

__device__ __forceinline__ float lae(float a, float b) {
    float mx = fmaxf(a, b);
    return mx + __logf(__expf(a - mx) + __expf(b - mx));
}
__device__ __forceinline__ float lae3(float a, float b, float c) {
    float mx = fmaxf(fmaxf(a, b), c);
    return mx + __logf(__expf(a - mx) + __expf(b - mx) + __expf(c - mx));
}
__device__ __forceinline__ float tanh_fast(float x) {
    float ex = __expf(2.f * x);
    return 1.f - 2.f / (ex + 1.f);
}

// ---------------- pack fp32 (K x N) weight into bf16 MFMA B-fragment order.
__device__ __forceinline__ void pack_seg(const float* __restrict__ W, bf16_t* __restrict__ Wf,
                                         int e, int K32, int N)
{
    int j  = e & 7;
    int l  = (e >> 3) & 63;
    int kk = (e >> 9) % K32;
    int nt = e / (K32 * 512);
    int v = nt * 16 + (l & 15);
    int k = kk * 32 + ((l >> 4) << 2) + (j & 3) + ((j >> 2) << 4);
    Wf[e] = (bf16_t)W[(size_t)k * N + v];
}

__global__ void pack_all(const float* __restrict__ Wout, const float* __restrict__ Wenc,
                         const float* __restrict__ Wpred, const float* __restrict__ Wctc,
                         bf16_t* __restrict__ FOut, bf16_t* __restrict__ FEnc,
                         bf16_t* __restrict__ FPred, bf16_t* __restrict__ FCtc)
{
    int e = blockIdx.x * 256 + threadIdx.x;
    if (e < 655360) { pack_seg(Wout, FOut, e, 20, 1024); return; }
    e -= 655360;
    if (e < 327680) { pack_seg(Wenc, FEnc, e, 16, 640); return; }
    e -= 327680;
    if (e < 409600) { pack_seg(Wpred, FPred, e, 20, 640); return; }
    e -= 409600;
    pack_seg(Wctc, FCtc, e, 16, 1024);
}

// ---------------- generic MFMA GEMM: C = A(MxK fp32) @ Wf(packed bf16) -----
template<int K32, int L, bool LSE>
__device__ void gemm_dev(const float* __restrict__ A, int M, int rowbase, int K,
                         const bf16_t* __restrict__ Wf, const float* __restrict__ bias,
                         float* __restrict__ C, float* __restrict__ lse_out, int N,
                         bf16_t* Atile, float (*ps)[8])
{
    const int tid = threadIdx.x;
#pragma unroll
    for (int it = 0; it < K32 / 2; ++it) {
        int fi = it * 512 + tid;
        int l = fi & 63, jk = fi >> 6;
        int j = jk / K32, kk = jk - j * K32;
        int row = rowbase + j * 16 + (l & 15);
        if (row > M - 1) row = M - 1;
        int c0 = kk * 32 + ((l >> 4) << 2);
        const float4 a0 = *(const float4*)&A[(size_t)row * K + c0];
        const float4 a1 = *(const float4*)&A[(size_t)row * K + c0 + 16];
        bf16x8 v;
        v[0] = (bf16_t)a0.x; v[1] = (bf16_t)a0.y; v[2] = (bf16_t)a0.z; v[3] = (bf16_t)a0.w;
        v[4] = (bf16_t)a1.x; v[5] = (bf16_t)a1.y; v[6] = (bf16_t)a1.z; v[7] = (bf16_t)a1.w;
        *(bf16x8*)&Atile[(size_t)fi * 8] = v;
    }
    __syncthreads();

    const int l = tid & 63, w = tid >> 6;
    const int lrow = l & 15, lhi = l >> 4;

    f32x4 acc[4][L];
#pragma unroll
    for (int j = 0; j < 4; ++j)
#pragma unroll
        for (int li = 0; li < L; ++li) acc[j][li] = f32x4{0.f, 0.f, 0.f, 0.f};

    for (int kk = 0; kk < K32; ++kk) {
        bf16x8 a[4];
#pragma unroll
        for (int j = 0; j < 4; ++j)
            a[j] = *(const bf16x8*)&Atile[(size_t)(((j * K32 + kk) * 64 + l) * 8)];
#pragma unroll
        for (int li = 0; li < L; ++li) {
            bf16x8 b = *(const bf16x8*)&Wf[(size_t)(((w * L + li) * K32 + kk) * 64 + l) * 8];
#pragma unroll
            for (int j = 0; j < 4; ++j)
                acc[j][li] = __builtin_amdgcn_mfma_f32_16x16x32_bf16(a[j], b, acc[j][li], 0, 0, 0);
        }
    }

    float se[4][4];
    if (LSE) {
#pragma unroll
        for (int j = 0; j < 4; ++j)
#pragma unroll
            for (int i = 0; i < 4; ++i) se[j][i] = 0.f;
    }
#pragma unroll
    for (int j = 0; j < 4; ++j)
#pragma unroll
        for (int li = 0; li < L; ++li) {
            int col = (w * L + li) * 16 + lrow;
            float bv = bias ? bias[col] : 0.f;
#pragma unroll
            for (int i = 0; i < 4; ++i) {
                int grow = rowbase + 16 * j + lhi * 4 + i;
                float x = acc[j][li][i] + bv;
                if (grow < M) C[(size_t)grow * N + col] = x;
                if (LSE) se[j][i] += __expf(x);
            }
        }
    if (LSE) {
#pragma unroll
        for (int d = 1; d < 16; d <<= 1)
#pragma unroll
            for (int j = 0; j < 4; ++j)
#pragma unroll
                for (int i = 0; i < 4; ++i) se[j][i] += __shfl_xor(se[j][i], d);
        if (lrow == 0) {
#pragma unroll
            for (int j = 0; j < 4; ++j)
#pragma unroll
                for (int i = 0; i < 4; ++i) ps[16 * j + lhi * 4 + i][w] = se[j][i];
        }
        __syncthreads();
        if (tid < 64) {
            float s = 0.f;
#pragma unroll
            for (int w0 = 0; w0 < 8; ++w0) s += ps[tid][w0];
            int grow = rowbase + tid;
            if (grow < M) lse_out[grow] = __logf(s);
        }
    }
}

__global__ __launch_bounds__(512)
void mfma_gemm3(const float* __restrict__ x_enc, const float* __restrict__ x_dec,
                const bf16_t* __restrict__ FEnc, const bf16_t* __restrict__ FPred,
                const bf16_t* __restrict__ FCtc, const float* __restrict__ b_ctc,
                float* __restrict__ enc_proj, float* __restrict__ pred_proj,
                float* __restrict__ ctc_logits, float* __restrict__ ctc_lse)
{
    __shared__ bf16_t Atile[40960];
    __shared__ float ps[64][8];
    int blk = blockIdx.x;
    if (blk < 13)
        gemm_dev<16, 5, false>(x_enc, 800, blk * 64, 512, FEnc, nullptr, enc_proj, nullptr, 640, Atile, ps);
    else if (blk < 17)
        gemm_dev<20, 5, false>(x_dec, 204, (blk - 13) * 64, 640, FPred, nullptr, pred_proj, nullptr, 640, Atile, ps);
    else
        gemm_dev<16, 8, true>(x_enc, 800, (blk - 17) * 64, 512, FCtc, b_ctc, ctc_logits, ctc_lse, 1024, Atile, ps);
}

// ---------------- fused joint build + MFMA GEMM + row-LSE + gather ---------
// LDS = exactly 80 KB (Afrag; reduction arrays overlay it after the K-loop)
// -> 2 blocks/CU, 4 waves/SIMD.
__global__ __launch_bounds__(512, 4)
void joint_gemm(const float* __restrict__ enc,   // (800,640)
                const float* __restrict__ pred,  // (204,640)
                const float* __restrict__ bj,    // (640)
                const bf16_t* __restrict__ Wf,   // packed (K32=20, NT=64)
                const float* __restrict__ bo,    // (1024)
                const int* __restrict__ target,  // (4,50)
                float* __restrict__ blank_buf, float* __restrict__ emit_buf)
{
    __shared__ __align__(16) char smbuf[81920];
    bf16_t* Afrag = (bf16_t*)smbuf;              // 64 rows x 640 K, frag order
    const int tid = threadIdx.x;
    const int blk = blockIdx.x;

    const int l = tid & 63, w = tid >> 6;
    const int lrow = l & 15, lhi = l >> 4;

    // build tanh(enc+pred+bj) tile; thread == fragment -> contiguous 16B
    // LDS writes (conflict-free). 5120 fragments / 512 threads = 10 iters.
    // b,t,u computed per-thread (no LDS row tables).
#pragma unroll
    for (int it = 0; it < 10; ++it) {
        int fi = it * 512 + tid;
        int ll = fi & 63, jk = fi >> 6;
        int j = jk / 20, kk = jk - j * 20;
        int row = j * 16 + (ll & 15);
        int r = blk * 64 + row; if (r > RTOT - 1) r = RTOT - 1;
        int b = r / (TT * U1); int rem = r - b * (TT * U1);
        int t = rem / U1;      int u = rem - t * U1;
        const float* erow = enc + (size_t)(b * TT + t) * HH;
        const float* prow = pred + (size_t)(b * U1 + u) * HH;
        int c0 = kk * 32 + ((ll >> 4) << 2);
        const float4 e0 = *(const float4*)&erow[c0];
        const float4 e1 = *(const float4*)&erow[c0 + 16];
        const float4 p0 = *(const float4*)&prow[c0];
        const float4 p1 = *(const float4*)&prow[c0 + 16];
        const float4 q0 = *(const float4*)&bj[c0];
        const float4 q1 = *(const float4*)&bj[c0 + 16];
        bf16x8 v;
        v[0] = (bf16_t)tanh_fast(e0.x + p0.x + q0.x);
        v[1] = (bf16_t)tanh_fast(e0.y + p0.y + q0.y);
        v[2] = (bf16_t)tanh_fast(e0.z + p0.z + q0.z);
        v[3] = (bf16_t)tanh_fast(e0.w + p0.w + q0.w);
        v[4] = (bf16_t)tanh_fast(e1.x + p1.x + q1.x);
        v[5] = (bf16_t)tanh_fast(e1.y + p1.y + q1.y);
        v[6] = (bf16_t)tanh_fast(e1.z + p1.z + q1.z);
        v[7] = (bf16_t)tanh_fast(e1.w + p1.w + q1.w);
        *(bf16x8*)&Afrag[(size_t)fi * 8] = v;
    }
    __syncthreads();

    f32x4 acc[4][8];
#pragma unroll
    for (int j = 0; j < 4; ++j)
#pragma unroll
        for (int li = 0; li < 8; ++li) acc[j][li] = f32x4{0.f, 0.f, 0.f, 0.f};

    const bf16_t* Bp = &Wf[(size_t)((w * 8 * 20) * 64 + l) * 8];

    // K loop, start offset rotated per block (L2 decorrelation)
    const int rot = blk % 20;
    for (int kk0 = 0; kk0 < 20; ++kk0) {
        int kk = kk0 + rot; if (kk >= 20) kk -= 20;
        bf16x8 a[4];
#pragma unroll
        for (int j = 0; j < 4; ++j)
            a[j] = *(const bf16x8*)&Afrag[(size_t)(((j * 20 + kk) * 64 + l) * 8)];
#pragma unroll
        for (int li = 0; li < 8; ++li) {
            bf16x8 b = *(const bf16x8*)(Bp + (size_t)li * 10240 + (size_t)kk * 512);
#pragma unroll
            for (int j = 0; j < 4; ++j)
                acc[j][li] = __builtin_amdgcn_mfma_f32_16x16x32_bf16(a[j], b, acc[j][li], 0, 0, 0);
        }
    }

    // per-thread target tokens for the 16 owned rows (direct global reads)
    int tg[4][4];
#pragma unroll
    for (int j = 0; j < 4; ++j)
#pragma unroll
        for (int i = 0; i < 4; ++i) {
            int r = blk * 64 + 16 * j + lhi * 4 + i; if (r > RTOT - 1) r = RTOT - 1;
            int b = r / (TT * U1); int rem = r - b * (TT * U1);
            int u = rem % U1;
            tg[j][i] = (u < UU) ? target[b * UU + u] : -1;
        }

    float se[4][4], ee[4][4], bbv[4][4];
#pragma unroll
    for (int j = 0; j < 4; ++j)
#pragma unroll
        for (int i = 0; i < 4; ++i) { se[j][i] = 0.f; ee[j][i] = NEGV; bbv[j][i] = NEGV; }

#pragma unroll
    for (int li = 0; li < 8; ++li) {
        int col = (w * 8 + li) * 16 + lrow;
        float bv = bo[col];
#pragma unroll
        for (int j = 0; j < 4; ++j)
#pragma unroll
            for (int i = 0; i < 4; ++i) {
                float x = acc[j][li][i] + bv;
                se[j][i] += __expf(x);
                if (col == tg[j][i]) ee[j][i] = x;
                if (col == VV - 1) bbv[j][i] = x;
            }
    }
#pragma unroll
    for (int d = 1; d < 16; d <<= 1)
#pragma unroll
        for (int j = 0; j < 4; ++j)
#pragma unroll
            for (int i = 0; i < 4; ++i) {
                se[j][i] += __shfl_xor(se[j][i], d);
                ee[j][i] = fmaxf(ee[j][i], __shfl_xor(ee[j][i], d));
                bbv[j][i] = fmaxf(bbv[j][i], __shfl_xor(bbv[j][i], d));
            }

    // Afrag is dead; overlay the cross-wave reduction arrays into its space.
    __syncthreads();
    float (*ps)[8] = (float (*)[8])(smbuf);
    float (*pe)[8] = (float (*)[8])(smbuf + 2048);
    float (*pb)[8] = (float (*)[8])(smbuf + 4096);
    if (lrow == 0) {
#pragma unroll
        for (int j = 0; j < 4; ++j)
#pragma unroll
            for (int i = 0; i < 4; ++i) {
                int r = 16 * j + lhi * 4 + i;
                ps[r][w] = se[j][i]; pe[r][w] = ee[j][i]; pb[r][w] = bbv[j][i];
            }
    }
    __syncthreads();
    if (tid < 64) {
        float s = 0.f, e = NEGV, bq = NEGV;
#pragma unroll
        for (int w0 = 0; w0 < 8; ++w0) {
            s += ps[tid][w0];
            e = fmaxf(e, pe[tid][w0]);
            bq = fmaxf(bq, pb[tid][w0]);
        }
        float lse = __logf(s);
        int gid = blk * 64 + tid;
        if (gid < RTOT) {
            blank_buf[gid] = bq - lse;
            emit_buf[gid]  = e - lse;
        }
    }
}

// ---------------- fused DPs: blocks 0-3 RNNT (wavefront), 4-7 CTC ----------
__global__ void dp_fused(const float* __restrict__ blank_buf, const float* __restrict__ emit_buf,
                         const float* __restrict__ ctc_logits, const float* __restrict__ ctc_lse,
                         const int* __restrict__ target, const int* __restrict__ frame_len,
                         const int* __restrict__ tgt_len,
                         float* __restrict__ loss_rnnt, float* __restrict__ loss_ctc)
{
    __shared__ float sm[20864];
    const int bid = blockIdx.x;
    const int u = threadIdx.x;   // 64

    if (bid < 4) {
        // ---- RNNT anti-diagonal wavefront: lane u owns column u ----
        // LDS layout [t][52] float2: coalesced global reads (uu lane-inner),
        // ~2-way write banks, ~4-way read banks in the d-loop (cheap).
        const int b = bid;
        float2* pk = (float2*)sm;    // [200][52] + pad
        for (int i = u; i < TT * U1; i += 64) {
            int t = i / U1, uu = i - t * U1;
            float bl = blank_buf[(b * TT + t) * U1 + uu];
            float em = emit_buf[(b * TT + t) * U1 + uu];
            pk[t * 52 + uu] = make_float2(bl, em);
        }
        __syncthreads();
        const int fl = frame_len[b], tl = tgt_len[b];
        float A = (u == 0) ? 0.f : NEGV;     // alpha[0][0]=0
        if (fl == 1 && tl == 0 && u == 0) loss_rnnt[b] = -(A + pk[0].x);
        for (int d = 1; d <= TT + U1 - 2; ++d) {
            int x = d - 1 - u;
            int xc = min(max(x, 0), TT - 1);
            int uc = min(u, 51);
            float2 be = pk[xc * 52 + uc];
            float vshare = A + be.y;
            float left = __shfl_up(vshare, 1);
            if (u == 0) left = NEGV;
            int t_new = d - u;
            if (u < U1 && t_new >= 0 && t_new < TT) {
                float up = (t_new >= 1) ? (A + be.x) : NEGV;
                A = lae(up, left);
                if (t_new == fl - 1 && u == tl)
                    loss_rnnt[b] = -(A + pk[t_new * 52 + u].x);
            }
        }
    } else {
        // ---- CTC: 2 states per lane, 200 serial t-steps ----
        const int b = bid - 4;
        float* lpE  = sm;
        float* lseB = sm + 200;
        float (*lpO)[52] = (float(*)[52])(sm + 400);
        for (int idx = u; idx < 200; idx += 64) {
            int bt = b * 200 + idx;
            float ls = ctc_lse[bt];
            lseB[idx] = ls;
            lpE[idx] = ctc_logits[(size_t)bt * VV + (VV - 1)] - ls;
        }
        for (int idx = u; idx < 200 * 50; idx += 64) {
            int t = idx / 50, uu = idx - t * 50;
            int tok = target[b * UU + uu];
            lpO[t][uu] = ctc_logits[(size_t)(b * 200 + t) * VV + tok];
        }
        __syncthreads();
        const int fl = frame_len[b], tl = tgt_len[b];
        bool skip = false;
        if (u >= 1 && u < UU) skip = (target[b * UU + u] != target[b * UU + u - 1]);

        float old_e = (u == 0) ? lpE[0] : NEGV;
        float old_o = (u == 0) ? (lpO[0][0] - lseB[0]) : NEGV;
        if (fl == 1 && u == 0) {
            float a_last = __shfl(old_e, tl);
            float a_prev = __shfl(old_o, tl - 1);
            loss_ctc[b] = -lae(a_last, a_prev);
        }
        for (int t = 1; t < 200; ++t) {
            float prev_o = __shfl_up(old_o, 1);
            if (u == 0) prev_o = NEGV;
            float lp_e = lpE[t];
            float lp_o = (u < UU) ? (lpO[t][u] - lseB[t]) : NEGV;
            float ne = lp_e + lae(old_e, prev_o);
            float no = lp_o + lae3(old_o, old_e, skip ? prev_o : NEGV);
            if (u > 50) ne = NEGV;
            if (u >= 50) no = NEGV;
            old_e = ne; old_o = no;
            if (t == fl - 1) {
                float a_last = __shfl(old_e, tl);
                float a_prev = __shfl(old_o, tl - 1);
                if (u == 0) loss_ctc[b] = -lae(a_last, a_prev);
            }
        }
    }
}

// ---------------- final combine -------------------------------------------
__global__ void combine(const float* __restrict__ lr, const float* __restrict__ lc,
                        float* __restrict__ out)
{
    float r = 0.25f * (lr[0] + lr[1] + lr[2] + lr[3]);
    float c = 0.25f * (lc[0] + lc[1] + lc[2] + lc[3]);
    out[0] = r + 0.3f * c;
}

extern "C" void kernel_launch(void* const* d_in, const int* in_sizes, int n_in,
                              void* d_out, int out_size, void* d_ws, size_t ws_size,
                              hipStream_t stream)
{
    const float* x_enc   = (const float*)d_in[0];
    const float* x_dec   = (const float*)d_in[1];
    const int*   target  = (const int*)d_in[2];
    const int*   frame_l = (const int*)d_in[3];
    const int*   tgt_l   = (const int*)d_in[4];
    const float* W_ctc   = (const float*)d_in[5];
    const float* b_ctc   = (const float*)d_in[6];
    const float* W_enc   = (const float*)d_in[7];
    const float* W_pred  = (const float*)d_in[8];
    const float* b_joint = (const float*)d_in[9];
    const float* W_out   = (const float*)d_in[10];
    const float* b_out   = (const float*)d_in[11];
    float* out = (float*)d_out;

    float* wsf        = (float*)d_ws;
    float* enc_proj   = wsf;                       // 512000
    float* pred_proj  = wsf + 512000;              // 130560
    float* ctc_logits = wsf + 642560;              // 819200
    float* ctc_lse    = wsf + 1461760;             // 832
    float* blank_buf  = wsf + 1462592;             // 40832
    float* emit_buf   = wsf + 1503424;             // 40832
    float* loss_rnnt  = wsf + 1544256;             // 4
    float* loss_ctc   = wsf + 1544260;             // 4 (+pad to 1544272)
    bf16_t* FOut  = (bf16_t*)(wsf + 1544272);      // 655360 bf16
    bf16_t* FEnc  = (bf16_t*)(wsf + 1871952);      // 327680 bf16
    bf16_t* FPred = (bf16_t*)(wsf + 2035792);      // 409600 bf16
    bf16_t* FCtc  = (bf16_t*)(wsf + 2240592);      // 524288 bf16

    pack_all<<<7488, 256, 0, stream>>>(W_out, W_enc, W_pred, W_ctc, FOut, FEnc, FPred, FCtc);
    mfma_gemm3<<<30, 512, 0, stream>>>(x_enc, x_dec, FEnc, FPred, FCtc, b_ctc,
                                       enc_proj, pred_proj, ctc_logits, ctc_lse);
    joint_gemm<<<RPAD / 64, 512, 0, stream>>>(enc_proj, pred_proj, b_joint, FOut, b_out,
                                              target, blank_buf, emit_buf);
    dp_fused<<<8, 64, 0, stream>>>(blank_buf, emit_buf, ctc_logits, ctc_lse,
                                   target, frame_l, tgt_l, loss_rnnt, loss_ctc);
    combine<<<1, 1, 0, stream>>>(loss_rnnt, loss_ctc, out);
}

// Round 8
// 240.644 us; speedup vs baseline: 2.3556x; 2.3556x over previous
//
#include <hip/hip_runtime.h>
#include <hip/hip_bf16.h>

typedef __bf16 bf16_t;
typedef __attribute__((ext_vector_type(4))) __bf16 bf16x4;
typedef __attribute__((ext_vector_type(8))) __bf16 bf16x8;
typedef __attribute__((ext_vector_type(4))) float f32x4;

#define NEGV (-1e30f)

// Problem constants
#define BB 4
#define TT 200
#define UU 50
#define U1 51
#define VV 1024
#define DD 512
#define HH 640
#define RTOT (BB*TT*U1)      // 40800
#define RPAD 40832           // 638*64
#define SS 101

__device__ __forceinline__ float lae(float a, float b) {
    float mx = fmaxf(a, b);
    return mx + __logf(__expf(a - mx) + __expf(b - mx));
}
__device__ __forceinline__ float lae3(float a, float b, float c) {
    float mx = fmaxf(fmaxf(a, b), c);
    return mx + __logf(__expf(a - mx) + __expf(b - mx) + __expf(c - mx));
}
__device__ __forceinline__ float tanh_fast(float x) {
    float ex = __expf(2.f * x);
    return 1.f - 2.f / (ex + 1.f);
}

// ---------------- pack fp32 (K x N) weight into bf16 MFMA B-fragment order.
__device__ __forceinline__ void pack_seg(const float* __restrict__ W, bf16_t* __restrict__ Wf,
                                         int e, int K32, int N)
{
    int j  = e & 7;
    int l  = (e >> 3) & 63;
    int kk = (e >> 9) % K32;
    int nt = e / (K32 * 512);
    int v = nt * 16 + (l & 15);
    int k = kk * 32 + ((l >> 4) << 2) + (j & 3) + ((j >> 2) << 4);
    Wf[e] = (bf16_t)W[(size_t)k * N + v];
}

__global__ void pack_all(const float* __restrict__ Wout, const float* __restrict__ Wenc,
                         const float* __restrict__ Wpred, const float* __restrict__ Wctc,
                         bf16_t* __restrict__ FOut, bf16_t* __restrict__ FEnc,
                         bf16_t* __restrict__ FPred, bf16_t* __restrict__ FCtc)
{
    int e = blockIdx.x * 256 + threadIdx.x;
    if (e < 655360) { pack_seg(Wout, FOut, e, 20, 1024); return; }
    e -= 655360;
    if (e < 327680) { pack_seg(Wenc, FEnc, e, 16, 640); return; }
    e -= 327680;
    if (e < 409600) { pack_seg(Wpred, FPred, e, 20, 640); return; }
    e -= 409600;
    pack_seg(Wctc, FCtc, e, 16, 1024);
}

// ---------------- generic MFMA GEMM: C = A(MxK fp32) @ Wf(packed bf16) -----
// J = 16-row tiles per block (block covers J*16 rows), 512 threads / 8 waves.
template<int K32, int L, bool LSE, int J>
__device__ void gemm_dev(const float* __restrict__ A, int M, int rowbase, int K,
                         const bf16_t* __restrict__ Wf, const float* __restrict__ bias,
                         float* __restrict__ C, float* __restrict__ lse_out, int N,
                         bf16_t* Atile, float (*ps)[8])
{
    const int tid = threadIdx.x;
    // build A tile in fragment order; thread == fragment -> contiguous 16B
    // LDS writes (conflict-free ds_write_b128). J*K32*64 frags / 512 thr.
#pragma unroll
    for (int it = 0; it < J * K32 / 8; ++it) {
        int fi = it * 512 + tid;
        int l = fi & 63, jk = fi >> 6;
        int j = jk / K32, kk = jk - j * K32;
        int row = rowbase + j * 16 + (l & 15);
        if (row > M - 1) row = M - 1;
        int c0 = kk * 32 + ((l >> 4) << 2);
        const float4 a0 = *(const float4*)&A[(size_t)row * K + c0];
        const float4 a1 = *(const float4*)&A[(size_t)row * K + c0 + 16];
        bf16x8 v;
        v[0] = (bf16_t)a0.x; v[1] = (bf16_t)a0.y; v[2] = (bf16_t)a0.z; v[3] = (bf16_t)a0.w;
        v[4] = (bf16_t)a1.x; v[5] = (bf16_t)a1.y; v[6] = (bf16_t)a1.z; v[7] = (bf16_t)a1.w;
        *(bf16x8*)&Atile[(size_t)fi * 8] = v;
    }
    __syncthreads();

    const int l = tid & 63, w = tid >> 6;
    const int lrow = l & 15, lhi = l >> 4;

    f32x4 acc[J][L];
#pragma unroll
    for (int j = 0; j < J; ++j)
#pragma unroll
        for (int li = 0; li < L; ++li) acc[j][li] = f32x4{0.f, 0.f, 0.f, 0.f};

    for (int kk = 0; kk < K32; ++kk) {
        bf16x8 a[J];
#pragma unroll
        for (int j = 0; j < J; ++j)
            a[j] = *(const bf16x8*)&Atile[(size_t)(((j * K32 + kk) * 64 + l) * 8)];
#pragma unroll
        for (int li = 0; li < L; ++li) {
            bf16x8 b = *(const bf16x8*)&Wf[(size_t)(((w * L + li) * K32 + kk) * 64 + l) * 8];
#pragma unroll
            for (int j = 0; j < J; ++j)
                acc[j][li] = __builtin_amdgcn_mfma_f32_16x16x32_bf16(a[j], b, acc[j][li], 0, 0, 0);
        }
    }

    float se[J][4];
    if (LSE) {
#pragma unroll
        for (int j = 0; j < J; ++j)
#pragma unroll
            for (int i = 0; i < 4; ++i) se[j][i] = 0.f;
    }
#pragma unroll
    for (int j = 0; j < J; ++j)
#pragma unroll
        for (int li = 0; li < L; ++li) {
            int col = (w * L + li) * 16 + lrow;
            float bv = bias ? bias[col] : 0.f;
#pragma unroll
            for (int i = 0; i < 4; ++i) {
                int grow = rowbase + 16 * j + lhi * 4 + i;
                float x = acc[j][li][i] + bv;
                if (grow < M) C[(size_t)grow * N + col] = x;
                if (LSE) se[j][i] += __expf(x);
            }
        }
    if (LSE) {
#pragma unroll
        for (int d = 1; d < 16; d <<= 1)
#pragma unroll
            for (int j = 0; j < J; ++j)
#pragma unroll
                for (int i = 0; i < 4; ++i) se[j][i] += __shfl_xor(se[j][i], d);
        if (lrow == 0) {
#pragma unroll
            for (int j = 0; j < J; ++j)
#pragma unroll
                for (int i = 0; i < 4; ++i) ps[16 * j + lhi * 4 + i][w] = se[j][i];
        }
        __syncthreads();
        if (tid < J * 16) {
            float s = 0.f;
#pragma unroll
            for (int w0 = 0; w0 < 8; ++w0) s += ps[tid][w0];
            int grow = rowbase + tid;
            if (grow < M) lse_out[grow] = __logf(s);
        }
    }
}

__global__ __launch_bounds__(512)
void mfma_gemm3(const float* __restrict__ x_enc, const float* __restrict__ x_dec,
                const bf16_t* __restrict__ FEnc, const bf16_t* __restrict__ FPred,
                const bf16_t* __restrict__ FCtc, const float* __restrict__ b_ctc,
                float* __restrict__ enc_proj, float* __restrict__ pred_proj,
                float* __restrict__ ctc_logits, float* __restrict__ ctc_lse)
{
    __shared__ bf16_t Atile[20480];   // J=2 max: 2*20*64*8
    __shared__ float ps[32][8];
    int blk = blockIdx.x;
    if (blk < 25)
        gemm_dev<16, 5, false, 2>(x_enc, 800, blk * 32, 512, FEnc, nullptr, enc_proj, nullptr, 640, Atile, ps);
    else if (blk < 32)
        gemm_dev<20, 5, false, 2>(x_dec, 204, (blk - 25) * 32, 640, FPred, nullptr, pred_proj, nullptr, 640, Atile, ps);
    else
        gemm_dev<16, 8, true, 2>(x_enc, 800, (blk - 32) * 32, 512, FCtc, b_ctc, ctc_logits, ctc_lse, 1024, Atile, ps);
}

// ---------------- fused joint build + MFMA GEMM + row-LSE + gather ---------
// 1024 threads / 16 waves, each wave 4 N-tiles -> acc[4][4]=64 VGPR.
// 16 waves/CU = 4 waves/SIMD. LDS 80KB (overlay reductions post-K).
__global__ __launch_bounds__(1024, 4)
void joint_gemm(const float* __restrict__ enc,   // (800,640)
                const float* __restrict__ pred,  // (204,640)
                const float* __restrict__ bj,    // (640)
                const bf16_t* __restrict__ Wf,   // packed (K32=20, NT=64)
                const float* __restrict__ bo,    // (1024)
                const int* __restrict__ target,  // (4,50)
                float* __restrict__ blank_buf, float* __restrict__ emit_buf)
{
    __shared__ __align__(16) char smbuf[81920];
    bf16_t* Afrag = (bf16_t*)smbuf;              // 64 rows x 640 K, frag order
    const int tid = threadIdx.x;
    const int blk = blockIdx.x;

    const int l = tid & 63, w = tid >> 6;        // w in 0..15
    const int lrow = l & 15, lhi = l >> 4;

    // build tanh(enc+pred+bj) tile; thread == fragment -> contiguous 16B
    // LDS writes (conflict-free). 5120 fragments / 1024 threads = 5 iters.
#pragma unroll
    for (int it = 0; it < 5; ++it) {
        int fi = it * 1024 + tid;
        int ll = fi & 63, jk = fi >> 6;
        int j = jk / 20, kk = jk - j * 20;
        int row = j * 16 + (ll & 15);
        int r = blk * 64 + row; if (r > RTOT - 1) r = RTOT - 1;
        int b = r / (TT * U1); int rem = r - b * (TT * U1);
        int t = rem / U1;      int u = rem - t * U1;
        const float* erow = enc + (size_t)(b * TT + t) * HH;
        const float* prow = pred + (size_t)(b * U1 + u) * HH;
        int c0 = kk * 32 + ((ll >> 4) << 2);
        const float4 e0 = *(const float4*)&erow[c0];
        const float4 e1 = *(const float4*)&erow[c0 + 16];
        const float4 p0 = *(const float4*)&prow[c0];
        const float4 p1 = *(const float4*)&prow[c0 + 16];
        const float4 q0 = *(const float4*)&bj[c0];
        const float4 q1 = *(const float4*)&bj[c0 + 16];
        bf16x8 v;
        v[0] = (bf16_t)tanh_fast(e0.x + p0.x + q0.x);
        v[1] = (bf16_t)tanh_fast(e0.y + p0.y + q0.y);
        v[2] = (bf16_t)tanh_fast(e0.z + p0.z + q0.z);
        v[3] = (bf16_t)tanh_fast(e0.w + p0.w + q0.w);
        v[4] = (bf16_t)tanh_fast(e1.x + p1.x + q1.x);
        v[5] = (bf16_t)tanh_fast(e1.y + p1.y + q1.y);
        v[6] = (bf16_t)tanh_fast(e1.z + p1.z + q1.z);
        v[7] = (bf16_t)tanh_fast(e1.w + p1.w + q1.w);
        *(bf16x8*)&Afrag[(size_t)fi * 8] = v;
    }
    __syncthreads();

    f32x4 acc[4][4];
#pragma unroll
    for (int j = 0; j < 4; ++j)
#pragma unroll
        for (int li = 0; li < 4; ++li) acc[j][li] = f32x4{0.f, 0.f, 0.f, 0.f};

    const bf16_t* Bp = &Wf[(size_t)(w * 4) * 10240 + (size_t)l * 8];

    // K loop, start offset rotated per block (L2 decorrelation)
    const int rot = blk % 20;
    for (int kk0 = 0; kk0 < 20; ++kk0) {
        int kk = kk0 + rot; if (kk >= 20) kk -= 20;
        bf16x8 a[4];
#pragma unroll
        for (int j = 0; j < 4; ++j)
            a[j] = *(const bf16x8*)&Afrag[(size_t)(((j * 20 + kk) * 64 + l) * 8)];
#pragma unroll
        for (int li = 0; li < 4; ++li) {
            bf16x8 b = *(const bf16x8*)(Bp + (size_t)li * 10240 + (size_t)kk * 512);
#pragma unroll
            for (int j = 0; j < 4; ++j)
                acc[j][li] = __builtin_amdgcn_mfma_f32_16x16x32_bf16(a[j], b, acc[j][li], 0, 0, 0);
        }
    }

    // per-thread target tokens for the 16 owned rows (direct global reads)
    int tg[4][4];
#pragma unroll
    for (int j = 0; j < 4; ++j)
#pragma unroll
        for (int i = 0; i < 4; ++i) {
            int r = blk * 64 + 16 * j + lhi * 4 + i; if (r > RTOT - 1) r = RTOT - 1;
            int b = r / (TT * U1); int rem = r - b * (TT * U1);
            int u = rem % U1;
            tg[j][i] = (u < UU) ? target[b * UU + u] : -1;
        }

    float se[4][4], ee[4][4], bbv[4][4];
#pragma unroll
    for (int j = 0; j < 4; ++j)
#pragma unroll
        for (int i = 0; i < 4; ++i) { se[j][i] = 0.f; ee[j][i] = NEGV; bbv[j][i] = NEGV; }

#pragma unroll
    for (int li = 0; li < 4; ++li) {
        int col = (w * 4 + li) * 16 + lrow;
        float bv = bo[col];
#pragma unroll
        for (int j = 0; j < 4; ++j)
#pragma unroll
            for (int i = 0; i < 4; ++i) {
                float x = acc[j][li][i] + bv;
                se[j][i] += __expf(x);
                if (col == tg[j][i]) ee[j][i] = x;
                if (col == VV - 1) bbv[j][i] = x;
            }
    }
#pragma unroll
    for (int d = 1; d < 16; d <<= 1)
#pragma unroll
        for (int j = 0; j < 4; ++j)
#pragma unroll
            for (int i = 0; i < 4; ++i) {
                se[j][i] += __shfl_xor(se[j][i], d);
                ee[j][i] = fmaxf(ee[j][i], __shfl_xor(ee[j][i], d));
                bbv[j][i] = fmaxf(bbv[j][i], __shfl_xor(bbv[j][i], d));
            }

    // Afrag is dead; overlay cross-wave reduction arrays [64][16] in LDS.
    __syncthreads();
    float (*ps)[16] = (float (*)[16])(smbuf);
    float (*pe)[16] = (float (*)[16])(smbuf + 4096);
    float (*pb)[16] = (float (*)[16])(smbuf + 8192);
    if (lrow == 0) {
#pragma unroll
        for (int j = 0; j < 4; ++j)
#pragma unroll
            for (int i = 0; i < 4; ++i) {
                int r = 16 * j + lhi * 4 + i;
                ps[r][w] = se[j][i]; pe[r][w] = ee[j][i]; pb[r][w] = bbv[j][i];
            }
    }
    __syncthreads();
    if (tid < 64) {
        float s = 0.f, e = NEGV, bq = NEGV;
#pragma unroll
        for (int w0 = 0; w0 < 16; ++w0) {
            s += ps[tid][w0];
            e = fmaxf(e, pe[tid][w0]);
            bq = fmaxf(bq, pb[tid][w0]);
        }
        float lse = __logf(s);
        int gid = blk * 64 + tid;
        if (gid < RTOT) {
            blank_buf[gid] = bq - lse;
            emit_buf[gid]  = e - lse;
        }
    }
}

// ---------------- fused DPs: blocks 0-3 RNNT (wavefront), 4-7 CTC ----------
__global__ void dp_fused(const float* __restrict__ blank_buf, const float* __restrict__ emit_buf,
                         const float* __restrict__ ctc_logits, const float* __restrict__ ctc_lse,
                         const int* __restrict__ target, const int* __restrict__ frame_len,
                         const int* __restrict__ tgt_len,
                         float* __restrict__ loss_rnnt, float* __restrict__ loss_ctc)
{
    __shared__ float sm[20864];
    const int bid = blockIdx.x;
    const int u = threadIdx.x;   // 64

    if (bid < 4) {
        // ---- RNNT anti-diagonal wavefront: lane u owns column u ----
        const int b = bid;
        float2* pk = (float2*)sm;    // [200][52]
        for (int i = u; i < TT * U1; i += 64) {
            int t = i / U1, uu = i - t * U1;
            float bl = blank_buf[(b * TT + t) * U1 + uu];
            float em = emit_buf[(b * TT + t) * U1 + uu];
            pk[t * 52 + uu] = make_float2(bl, em);
        }
        __syncthreads();
        const int fl = frame_len[b], tl = tgt_len[b];
        float A = (u == 0) ? 0.f : NEGV;     // alpha[0][0]=0
        if (fl == 1 && tl == 0 && u == 0) loss_rnnt[b] = -(A + pk[0].x);
        for (int d = 1; d <= TT + U1 - 2; ++d) {
            int x = d - 1 - u;
            int xc = min(max(x, 0), TT - 1);
            int uc = min(u, 51);
            float2 be = pk[xc * 52 + uc];
            float vshare = A + be.y;
            float left = __shfl_up(vshare, 1);
            if (u == 0) left = NEGV;
            int t_new = d - u;
            if (u < U1 && t_new >= 0 && t_new < TT) {
                float up = (t_new >= 1) ? (A + be.x) : NEGV;
                A = lae(up, left);
                if (t_new == fl - 1 && u == tl)
                    loss_rnnt[b] = -(A + pk[t_new * 52 + u].x);
            }
        }
    } else {
        // ---- CTC: 2 states per lane, 200 serial t-steps ----
        const int b = bid - 4;
        float* lpE  = sm;
        float* lseB = sm + 200;
        float (*lpO)[52] = (float(*)[52])(sm + 400);
        for (int idx = u; idx < 200; idx += 64) {
            int bt = b * 200 + idx;
            float ls = ctc_lse[bt];
            lseB[idx] = ls;
            lpE[idx] = ctc_logits[(size_t)bt * VV + (VV - 1)] - ls;
        }
        for (int idx = u; idx < 200 * 50; idx += 64) {
            int t = idx / 50, uu = idx - t * 50;
            int tok = target[b * UU + uu];
            lpO[t][uu] = ctc_logits[(size_t)(b * 200 + t) * VV + tok];
        }
        __syncthreads();
        const int fl = frame_len[b], tl = tgt_len[b];
        bool skip = false;
        if (u >= 1 && u < UU) skip = (target[b * UU + u] != target[b * UU + u - 1]);

        float old_e = (u == 0) ? lpE[0] : NEGV;
        float old_o = (u == 0) ? (lpO[0][0] - lseB[0]) : NEGV;
        if (fl == 1 && u == 0) {
            float a_last = __shfl(old_e, tl);
            float a_prev = __shfl(old_o, tl - 1);
            loss_ctc[b] = -lae(a_last, a_prev);
        }
        for (int t = 1; t < 200; ++t) {
            float prev_o = __shfl_up(old_o, 1);
            if (u == 0) prev_o = NEGV;
            float lp_e = lpE[t];
            float lp_o = (u < UU) ? (lpO[t][u] - lseB[t]) : NEGV;
            float ne = lp_e + lae(old_e, prev_o);
            float no = lp_o + lae3(old_o, old_e, skip ? prev_o : NEGV);
            if (u > 50) ne = NEGV;
            if (u >= 50) no = NEGV;
            old_e = ne; old_o = no;
            if (t == fl - 1) {
                float a_last = __shfl(old_e, tl);
                float a_prev = __shfl(old_o, tl - 1);
                if (u == 0) loss_ctc[b] = -lae(a_last, a_prev);
            }
        }
    }
}

// ---------------- final combine -------------------------------------------
__global__ void combine(const float* __restrict__ lr, const float* __restrict__ lc,
                        float* __restrict__ out)
{
    float r = 0.25f * (lr[0] + lr[1] + lr[2] + lr[3]);
    float c = 0.25f * (lc[0] + lc[1] + lc[2] + lc[3]);
    out[0] = r + 0.3f * c;
}

extern "C" void kernel_launch(void* const* d_in, const int* in_sizes, int n_in,
                              void* d_out, int out_size, void* d_ws, size_t ws_size,
                              hipStream_t stream)
{
    const float* x_enc   = (const float*)d_in[0];
    const float* x_dec   = (const float*)d_in[1];
    const int*   target  = (const int*)d_in[2];
    const int*   frame_l = (const int*)d_in[3];
    const int*   tgt_l   = (const int*)d_in[4];
    const float* W_ctc   = (const float*)d_in[5];
    const float* b_ctc   = (const float*)d_in[6];
    const float* W_enc   = (const float*)d_in[7];
    const float* W_pred  = (const float*)d_in[8];
    const float* b_joint = (const float*)d_in[9];
    const float* W_out   = (const float*)d_in[10];
    const float* b_out   = (const float*)d_in[11];
    float* out = (float*)d_out;

    float* wsf        = (float*)d_ws;
    float* enc_proj   = wsf;                       // 512000
    float* pred_proj  = wsf + 512000;              // 130560
    float* ctc_logits = wsf + 642560;              // 819200
    float* ctc_lse    = wsf + 1461760;             // 832
    float* blank_buf  = wsf + 1462592;             // 40832
    float* emit_buf   = wsf + 1503424;             // 40832
    float* loss_rnnt  = wsf + 1544256;             // 4
    float* loss_ctc   = wsf + 1544260;             // 4 (+pad to 1544272)
    bf16_t* FOut  = (bf16_t*)(wsf + 1544272);      // 655360 bf16
    bf16_t* FEnc  = (bf16_t*)(wsf + 1871952);      // 327680 bf16
    bf16_t* FPred = (bf16_t*)(wsf + 2035792);      // 409600 bf16
    bf16_t* FCtc  = (bf16_t*)(wsf + 2240592);      // 524288 bf16

    pack_all<<<7488, 256, 0, stream>>>(W_out, W_enc, W_pred, W_ctc, FOut, FEnc, FPred, FCtc);
    mfma_gemm3<<<57, 512, 0, stream>>>(x_enc, x_dec, FEnc, FPred, FCtc, b_ctc,
                                       enc_proj, pred_proj, ctc_logits, ctc_lse);
    joint_gemm<<<RPAD / 64, 1024, 0, stream>>>(enc_proj, pred_proj, b_joint, FOut, b_out,
                                               target, blank_buf, emit_buf);
    dp_fused<<<8, 64, 0, stream>>>(blank_buf, emit_buf, ctc_logits, ctc_lse,
                                   target, frame_l, tgt_l, loss_rnnt, loss_ctc);
    combine<<<1, 1, 0, stream>>>(loss_rnnt, loss_ctc, out);
}

// Round 9
// 232.621 us; speedup vs baseline: 2.4369x; 1.0345x over previous
//
#include <hip/hip_runtime.h>
#include <hip/hip_bf16.h>

typedef __bf16 bf16_t;
typedef __attribute__((ext_vector_type(4))) __bf16 bf16x4;
typedef __attribute__((ext_vector_type(8))) __bf16 bf16x8;
typedef __attribute__((ext_vector_type(4))) float f32x4;

#define NEGV (-1e30f)

// Problem constants
#define BB 4
#define TT 200
#define UU 50
#define U1 51
#define VV 1024
#define DD 512
#define HH 640
#define RTOT (BB*TT*U1)      // 40800
#define RPAD 40832           // 638*64
#define NJBLK 638
#define NCBLK 13             // ctc gemm blocks fused into joint launch
#define SS 101

__device__ __forceinline__ float lae(float a, float b) {
    float mx = fmaxf(a, b);
    return mx + __logf(__expf(a - mx) + __expf(b - mx));
}
__device__ __forceinline__ float lae3(float a, float b, float c) {
    float mx = fmaxf(fmaxf(a, b), c);
    return mx + __logf(__expf(a - mx) + __expf(b - mx) + __expf(c - mx));
}
__device__ __forceinline__ float tanh_fast(float x) {
    float ex = __expf(2.f * x);
    return 1.f - 2.f / (ex + 1.f);
}

// ---------------- pack fp32 (K x N) weight into bf16 MFMA B-fragment order.
__device__ __forceinline__ void pack_seg(const float* __restrict__ W, bf16_t* __restrict__ Wf,
                                         int e, int K32, int N)
{
    int j  = e & 7;
    int l  = (e >> 3) & 63;
    int kk = (e >> 9) % K32;
    int nt = e / (K32 * 512);
    int v = nt * 16 + (l & 15);
    int k = kk * 32 + ((l >> 4) << 2) + (j & 3) + ((j >> 2) << 4);
    Wf[e] = (bf16_t)W[(size_t)k * N + v];
}

__global__ void pack_all(const float* __restrict__ Wout, const float* __restrict__ Wenc,
                         const float* __restrict__ Wpred, const float* __restrict__ Wctc,
                         bf16_t* __restrict__ FOut, bf16_t* __restrict__ FEnc,
                         bf16_t* __restrict__ FPred, bf16_t* __restrict__ FCtc)
{
    int e = blockIdx.x * 256 + threadIdx.x;
    if (e < 655360) { pack_seg(Wout, FOut, e, 20, 1024); return; }
    e -= 655360;
    if (e < 327680) { pack_seg(Wenc, FEnc, e, 16, 640); return; }
    e -= 327680;
    if (e < 409600) { pack_seg(Wpred, FPred, e, 20, 640); return; }
    e -= 409600;
    pack_seg(Wctc, FCtc, e, 16, 1024);
}

// ---------------- generic MFMA GEMM: C = A(MxK fp32) @ Wf(packed bf16) -----
// J 16-row tiles per block, 512 threads / 8 waves, L N-tiles per wave.
template<int K32, int L, bool LSE, int J>
__device__ void gemm_dev(const float* __restrict__ A, int M, int rowbase, int K,
                         const bf16_t* __restrict__ Wf, const float* __restrict__ bias,
                         float* __restrict__ C, float* __restrict__ lse_out, int N,
                         bf16_t* Atile, float (*ps)[8])
{
    const int tid = threadIdx.x;
#pragma unroll
    for (int it = 0; it < J * K32 / 8; ++it) {
        int fi = it * 512 + tid;
        int l = fi & 63, jk = fi >> 6;
        int j = jk / K32, kk = jk - j * K32;
        int row = rowbase + j * 16 + (l & 15);
        if (row > M - 1) row = M - 1;
        int c0 = kk * 32 + ((l >> 4) << 2);
        const float4 a0 = *(const float4*)&A[(size_t)row * K + c0];
        const float4 a1 = *(const float4*)&A[(size_t)row * K + c0 + 16];
        bf16x8 v;
        v[0] = (bf16_t)a0.x; v[1] = (bf16_t)a0.y; v[2] = (bf16_t)a0.z; v[3] = (bf16_t)a0.w;
        v[4] = (bf16_t)a1.x; v[5] = (bf16_t)a1.y; v[6] = (bf16_t)a1.z; v[7] = (bf16_t)a1.w;
        *(bf16x8*)&Atile[(size_t)fi * 8] = v;
    }
    __syncthreads();

    const int l = tid & 63, w = tid >> 6;
    const int lrow = l & 15, lhi = l >> 4;

    f32x4 acc[J][L];
#pragma unroll
    for (int j = 0; j < J; ++j)
#pragma unroll
        for (int li = 0; li < L; ++li) acc[j][li] = f32x4{0.f, 0.f, 0.f, 0.f};

    for (int kk = 0; kk < K32; ++kk) {
        bf16x8 a[J];
#pragma unroll
        for (int j = 0; j < J; ++j)
            a[j] = *(const bf16x8*)&Atile[(size_t)(((j * K32 + kk) * 64 + l) * 8)];
#pragma unroll
        for (int li = 0; li < L; ++li) {
            bf16x8 b = *(const bf16x8*)&Wf[(size_t)(((w * L + li) * K32 + kk) * 64 + l) * 8];
#pragma unroll
            for (int j = 0; j < J; ++j)
                acc[j][li] = __builtin_amdgcn_mfma_f32_16x16x32_bf16(a[j], b, acc[j][li], 0, 0, 0);
        }
    }

    float se[J][4];
    if (LSE) {
#pragma unroll
        for (int j = 0; j < J; ++j)
#pragma unroll
            for (int i = 0; i < 4; ++i) se[j][i] = 0.f;
    }
#pragma unroll
    for (int j = 0; j < J; ++j)
#pragma unroll
        for (int li = 0; li < L; ++li) {
            int col = (w * L + li) * 16 + lrow;
            float bv = bias ? bias[col] : 0.f;
#pragma unroll
            for (int i = 0; i < 4; ++i) {
                int grow = rowbase + 16 * j + lhi * 4 + i;
                float x = acc[j][li][i] + bv;
                if (grow < M) C[(size_t)grow * N + col] = x;
                if (LSE) se[j][i] += __expf(x);
            }
        }
    if (LSE) {
#pragma unroll
        for (int d = 1; d < 16; d <<= 1)
#pragma unroll
            for (int j = 0; j < J; ++j)
#pragma unroll
                for (int i = 0; i < 4; ++i) se[j][i] += __shfl_xor(se[j][i], d);
        if (lrow == 0) {
#pragma unroll
            for (int j = 0; j < J; ++j)
#pragma unroll
                for (int i = 0; i < 4; ++i) ps[16 * j + lhi * 4 + i][w] = se[j][i];
        }
        __syncthreads();
        if (tid < J * 16) {
            float s = 0.f;
#pragma unroll
            for (int w0 = 0; w0 < 8; ++w0) s += ps[tid][w0];
            int grow = rowbase + tid;
            if (grow < M) lse_out[grow] = __logf(s);
        }
    }
}

// ---------------- enc/pred projections (small) -----------------------------
__global__ __launch_bounds__(512)
void proj_gemm(const float* __restrict__ x_enc, const float* __restrict__ x_dec,
               const bf16_t* __restrict__ FEnc, const bf16_t* __restrict__ FPred,
               float* __restrict__ enc_proj, float* __restrict__ pred_proj)
{
    __shared__ bf16_t Atile[40960];
    __shared__ float ps[64][8];
    int blk = blockIdx.x;
    if (blk < 13)
        gemm_dev<16, 5, false, 4>(x_enc, 800, blk * 64, 512, FEnc, nullptr, enc_proj, nullptr, 640, Atile, ps);
    else
        gemm_dev<20, 5, false, 4>(x_dec, 204, (blk - 13) * 64, 640, FPred, nullptr, pred_proj, nullptr, 640, Atile, ps);
}

// ---------------- fused joint build + MFMA GEMM + row-LSE + gather ---------
// blocks 0..637: joint rows; blocks 638..650: ctc logits GEMM (+row LSE).
__global__ __launch_bounds__(512)
void joint_gemm(const float* __restrict__ enc,   // (800,640)
                const float* __restrict__ pred,  // (204,640)
                const float* __restrict__ bj,    // (640)
                const bf16_t* __restrict__ Wf,   // packed (K32=20, NT=64)
                const float* __restrict__ bo,    // (1024)
                const int* __restrict__ target,  // (4,50)
                float* __restrict__ blank_buf, float* __restrict__ emit_buf,
                const float* __restrict__ x_enc, const bf16_t* __restrict__ FCtc,
                const float* __restrict__ b_ctc,
                float* __restrict__ ctc_logits, float* __restrict__ ctc_lse)
{
    __shared__ __align__(16) char smbuf[81920];
    const int tid = threadIdx.x;
    const int blk = blockIdx.x;

    if (blk >= NJBLK) {
        // ---- CTC logits GEMM (rides along on idle CUs) ----
        gemm_dev<16, 8, true, 4>(x_enc, 800, (blk - NJBLK) * 64, 512, FCtc, b_ctc,
                                 ctc_logits, ctc_lse, 1024,
                                 (bf16_t*)smbuf, (float (*)[8])(smbuf + 65536));
        return;
    }

    bf16_t* Afrag = (bf16_t*)smbuf;              // 64 rows x 640 K, frag order
    const int l = tid & 63, w = tid >> 6;
    const int lrow = l & 15, lhi = l >> 4;

    // build tanh(enc+pred+bj) tile; thread == fragment -> contiguous 16B
    // LDS writes (conflict-free). 5120 fragments / 512 threads = 10 iters.
#pragma unroll
    for (int it = 0; it < 10; ++it) {
        int fi = it * 512 + tid;
        int ll = fi & 63, jk = fi >> 6;
        int j = jk / 20, kk = jk - j * 20;
        int row = j * 16 + (ll & 15);
        int r = blk * 64 + row; if (r > RTOT - 1) r = RTOT - 1;
        int b = r / (TT * U1); int rem = r - b * (TT * U1);
        int t = rem / U1;      int u = rem - t * U1;
        const float* erow = enc + (size_t)(b * TT + t) * HH;
        const float* prow = pred + (size_t)(b * U1 + u) * HH;
        int c0 = kk * 32 + ((ll >> 4) << 2);
        const float4 e0 = *(const float4*)&erow[c0];
        const float4 e1 = *(const float4*)&erow[c0 + 16];
        const float4 p0 = *(const float4*)&prow[c0];
        const float4 p1 = *(const float4*)&prow[c0 + 16];
        const float4 q0 = *(const float4*)&bj[c0];
        const float4 q1 = *(const float4*)&bj[c0 + 16];
        bf16x8 v;
        v[0] = (bf16_t)tanh_fast(e0.x + p0.x + q0.x);
        v[1] = (bf16_t)tanh_fast(e0.y + p0.y + q0.y);
        v[2] = (bf16_t)tanh_fast(e0.z + p0.z + q0.z);
        v[3] = (bf16_t)tanh_fast(e0.w + p0.w + q0.w);
        v[4] = (bf16_t)tanh_fast(e1.x + p1.x + q1.x);
        v[5] = (bf16_t)tanh_fast(e1.y + p1.y + q1.y);
        v[6] = (bf16_t)tanh_fast(e1.z + p1.z + q1.z);
        v[7] = (bf16_t)tanh_fast(e1.w + p1.w + q1.w);
        *(bf16x8*)&Afrag[(size_t)fi * 8] = v;
    }
    __syncthreads();

    f32x4 acc[4][8];
#pragma unroll
    for (int j = 0; j < 4; ++j)
#pragma unroll
        for (int li = 0; li < 8; ++li) acc[j][li] = f32x4{0.f, 0.f, 0.f, 0.f};

    const bf16_t* Bp = &Wf[(size_t)((w * 8 * 20) * 64 + l) * 8];

    // K loop rotated per block (L2 decorrelation), split into two LINEAR
    // segments so all addresses strength-reduce to pointer increments.
    const int rot = blk % 20;
    auto kstep = [&](int kk) {
        bf16x8 a[4];
#pragma unroll
        for (int j = 0; j < 4; ++j)
            a[j] = *(const bf16x8*)&Afrag[(size_t)(((j * 20 + kk) * 64 + l) * 8)];
#pragma unroll
        for (int li = 0; li < 8; ++li) {
            bf16x8 b = *(const bf16x8*)(Bp + (size_t)li * 10240 + (size_t)kk * 512);
#pragma unroll
            for (int j = 0; j < 4; ++j)
                acc[j][li] = __builtin_amdgcn_mfma_f32_16x16x32_bf16(a[j], b, acc[j][li], 0, 0, 0);
        }
    };
    for (int kk = rot; kk < 20; ++kk) kstep(kk);
    for (int kk = 0; kk < rot; ++kk) kstep(kk);

    // per-thread target tokens for the 16 owned rows (direct global reads)
    int tg[4][4];
#pragma unroll
    for (int j = 0; j < 4; ++j)
#pragma unroll
        for (int i = 0; i < 4; ++i) {
            int r = blk * 64 + 16 * j + lhi * 4 + i; if (r > RTOT - 1) r = RTOT - 1;
            int b = r / (TT * U1); int rem = r - b * (TT * U1);
            int u = rem % U1;
            tg[j][i] = (u < UU) ? target[b * UU + u] : -1;
        }

    float se[4][4], ee[4][4], bbv[4][4];
#pragma unroll
    for (int j = 0; j < 4; ++j)
#pragma unroll
        for (int i = 0; i < 4; ++i) { se[j][i] = 0.f; ee[j][i] = NEGV; bbv[j][i] = NEGV; }

#pragma unroll
    for (int li = 0; li < 8; ++li) {
        int col = (w * 8 + li) * 16 + lrow;
        float bv = bo[col];
#pragma unroll
        for (int j = 0; j < 4; ++j)
#pragma unroll
            for (int i = 0; i < 4; ++i) {
                float x = acc[j][li][i] + bv;
                se[j][i] += __expf(x);
                if (col == tg[j][i]) ee[j][i] = x;
            }
    }
    // blank col (1023) lives only at w==7, li==7, lrow==15 (uniform guard)
    if (w == 7) {
        float bv = bo[1023];
#pragma unroll
        for (int j = 0; j < 4; ++j)
#pragma unroll
            for (int i = 0; i < 4; ++i) {
                float x = acc[j][7][i] + bv;
                if (lrow == 15) bbv[j][i] = x;
            }
    }
#pragma unroll
    for (int d = 1; d < 16; d <<= 1)
#pragma unroll
        for (int j = 0; j < 4; ++j)
#pragma unroll
            for (int i = 0; i < 4; ++i) {
                se[j][i] += __shfl_xor(se[j][i], d);
                ee[j][i] = fmaxf(ee[j][i], __shfl_xor(ee[j][i], d));
                bbv[j][i] = fmaxf(bbv[j][i], __shfl_xor(bbv[j][i], d));
            }

    // Afrag is dead; overlay cross-wave reduction arrays [64][8] in LDS.
    __syncthreads();
    float (*ps)[8] = (float (*)[8])(smbuf);
    float (*pe)[8] = (float (*)[8])(smbuf + 2048);
    float (*pb)[8] = (float (*)[8])(smbuf + 4096);
    if (lrow == 0) {
#pragma unroll
        for (int j = 0; j < 4; ++j)
#pragma unroll
            for (int i = 0; i < 4; ++i) {
                int r = 16 * j + lhi * 4 + i;
                ps[r][w] = se[j][i]; pe[r][w] = ee[j][i]; pb[r][w] = bbv[j][i];
            }
    }
    __syncthreads();
    if (tid < 64) {
        float s = 0.f, e = NEGV, bq = NEGV;
#pragma unroll
        for (int w0 = 0; w0 < 8; ++w0) {
            s += ps[tid][w0];
            e = fmaxf(e, pe[tid][w0]);
            bq = fmaxf(bq, pb[tid][w0]);
        }
        float lse = __logf(s);
        int gid = blk * 64 + tid;
        if (gid < RTOT) {
            blank_buf[gid] = bq - lse;
            emit_buf[gid]  = e - lse;
        }
    }
}

// ---------------- fused DPs: blocks 0-3 RNNT (wavefront), 4-7 CTC ----------
__global__ void dp_fused(const float* __restrict__ blank_buf, const float* __restrict__ emit_buf,
                         const float* __restrict__ ctc_logits, const float* __restrict__ ctc_lse,
                         const int* __restrict__ target, const int* __restrict__ frame_len,
                         const int* __restrict__ tgt_len,
                         float* __restrict__ loss_rnnt, float* __restrict__ loss_ctc)
{
    __shared__ float sm[20864];
    const int bid = blockIdx.x;
    const int u = threadIdx.x;   // 64

    if (bid < 4) {
        // ---- RNNT anti-diagonal wavefront: lane u owns column u ----
        const int b = bid;
        float2* pk = (float2*)sm;    // [200][52]
        for (int i = u; i < TT * U1; i += 64) {
            int t = i / U1, uu = i - t * U1;
            float bl = blank_buf[(b * TT + t) * U1 + uu];
            float em = emit_buf[(b * TT + t) * U1 + uu];
            pk[t * 52 + uu] = make_float2(bl, em);
        }
        __syncthreads();
        const int fl = frame_len[b], tl = tgt_len[b];
        float A = (u == 0) ? 0.f : NEGV;     // alpha[0][0]=0
        if (fl == 1 && tl == 0 && u == 0) loss_rnnt[b] = -(A + pk[0].x);
        for (int d = 1; d <= TT + U1 - 2; ++d) {
            int x = d - 1 - u;
            int xc = min(max(x, 0), TT - 1);
            int uc = min(u, 51);
            float2 be = pk[xc * 52 + uc];
            float vshare = A + be.y;
            float left = __shfl_up(vshare, 1);
            if (u == 0) left = NEGV;
            int t_new = d - u;
            if (u < U1 && t_new >= 0 && t_new < TT) {
                float up = (t_new >= 1) ? (A + be.x) : NEGV;
                A = lae(up, left);
                if (t_new == fl - 1 && u == tl)
                    loss_rnnt[b] = -(A + pk[t_new * 52 + u].x);
            }
        }
    } else {
        // ---- CTC: 2 states per lane, 200 serial t-steps ----
        const int b = bid - 4;
        float* lpE  = sm;
        float* lseB = sm + 200;
        float (*lpO)[52] = (float(*)[52])(sm + 400);
        for (int idx = u; idx < 200; idx += 64) {
            int bt = b * 200 + idx;
            float ls = ctc_lse[bt];
            lseB[idx] = ls;
            lpE[idx] = ctc_logits[(size_t)bt * VV + (VV - 1)] - ls;
        }
        for (int idx = u; idx < 200 * 50; idx += 64) {
            int t = idx / 50, uu = idx - t * 50;
            int tok = target[b * UU + uu];
            lpO[t][uu] = ctc_logits[(size_t)(b * 200 + t) * VV + tok];
        }
        __syncthreads();
        const int fl = frame_len[b], tl = tgt_len[b];
        bool skip = false;
        if (u >= 1 && u < UU) skip = (target[b * UU + u] != target[b * UU + u - 1]);

        float old_e = (u == 0) ? lpE[0] : NEGV;
        float old_o = (u == 0) ? (lpO[0][0] - lseB[0]) : NEGV;
        if (fl == 1 && u == 0) {
            float a_last = __shfl(old_e, tl);
            float a_prev = __shfl(old_o, tl - 1);
            loss_ctc[b] = -lae(a_last, a_prev);
        }
        for (int t = 1; t < 200; ++t) {
            float prev_o = __shfl_up(old_o, 1);
            if (u == 0) prev_o = NEGV;
            float lp_e = lpE[t];
            float lp_o = (u < UU) ? (lpO[t][u] - lseB[t]) : NEGV;
            float ne = lp_e + lae(old_e, prev_o);
            float no = lp_o + lae3(old_o, old_e, skip ? prev_o : NEGV);
            if (u > 50) ne = NEGV;
            if (u >= 50) no = NEGV;
            old_e = ne; old_o = no;
            if (t == fl - 1) {
                float a_last = __shfl(old_e, tl);
                float a_prev = __shfl(old_o, tl - 1);
                if (u == 0) loss_ctc[b] = -lae(a_last, a_prev);
            }
        }
    }
}

// ---------------- final combine -------------------------------------------
__global__ void combine(const float* __restrict__ lr, const float* __restrict__ lc,
                        float* __restrict__ out)
{
    float r = 0.25f * (lr[0] + lr[1] + lr[2] + lr[3]);
    float c = 0.25f * (lc[0] + lc[1] + lc[2] + lc[3]);
    out[0] = r + 0.3f * c;
}

extern "C" void kernel_launch(void* const* d_in, const int* in_sizes, int n_in,
                              void* d_out, int out_size, void* d_ws, size_t ws_size,
                              hipStream_t stream)
{
    const float* x_enc   = (const float*)d_in[0];
    const float* x_dec   = (const float*)d_in[1];
    const int*   target  = (const int*)d_in[2];
    const int*   frame_l = (const int*)d_in[3];
    const int*   tgt_l   = (const int*)d_in[4];
    const float* W_ctc   = (const float*)d_in[5];
    const float* b_ctc   = (const float*)d_in[6];
    const float* W_enc   = (const float*)d_in[7];
    const float* W_pred  = (const float*)d_in[8];
    const float* b_joint = (const float*)d_in[9];
    const float* W_out   = (const float*)d_in[10];
    const float* b_out   = (const float*)d_in[11];
    float* out = (float*)d_out;

    float* wsf        = (float*)d_ws;
    float* enc_proj   = wsf;                       // 512000
    float* pred_proj  = wsf + 512000;              // 130560
    float* ctc_logits = wsf + 642560;              // 819200
    float* ctc_lse    = wsf + 1461760;             // 832
    float* blank_buf  = wsf + 1462592;             // 40832
    float* emit_buf   = wsf + 1503424;             // 40832
    float* loss_rnnt  = wsf + 1544256;             // 4
    float* loss_ctc   = wsf + 1544260;             // 4 (+pad to 1544272)
    bf16_t* FOut  = (bf16_t*)(wsf + 1544272);      // 655360 bf16
    bf16_t* FEnc  = (bf16_t*)(wsf + 1871952);      // 327680 bf16
    bf16_t* FPred = (bf16_t*)(wsf + 2035792);      // 409600 bf16
    bf16_t* FCtc  = (bf16_t*)(wsf + 2240592);      // 524288 bf16

    pack_all<<<7488, 256, 0, stream>>>(W_out, W_enc, W_pred, W_ctc, FOut, FEnc, FPred, FCtc);
    proj_gemm<<<17, 512, 0, stream>>>(x_enc, x_dec, FEnc, FPred, enc_proj, pred_proj);
    joint_gemm<<<NJBLK + NCBLK, 512, 0, stream>>>(enc_proj, pred_proj, b_joint, FOut, b_out,
                                                  target, blank_buf, emit_buf,
                                                  x_enc, FCtc, b_ctc, ctc_logits, ctc_lse);
    dp_fused<<<8, 64, 0, stream>>>(blank_buf, emit_buf, ctc_logits, ctc_lse,
                                   target, frame_l, tgt_l, loss_rnnt, loss_ctc);
    combine<<<1, 1, 0, stream>>>(loss_rnnt, loss_ctc, out);
}

// Round 10
// 211.205 us; speedup vs baseline: 2.6840x; 1.1014x over previous
//
#include <hip/hip_runtime.h>
#include <hip/hip_bf16.h>

typedef __bf16 bf16_t;
typedef __attribute__((ext_vector_type(8))) __bf16 bf16x8;
typedef __attribute__((ext_vector_type(4))) float f32x4;
typedef __attribute__((ext_vector_type(2))) long long2_t;

#define NEGV (-1e30f)

// Problem constants
#define BB 4
#define TT 200
#define UU 50
#define U1 51
#define VV 1024
#define DD 512
#define HH 640
#define RTOT (BB*TT*U1)      // 40800
#define RPAD 40832           // 638*64
#define SS 101

__device__ __forceinline__ float lae(float a, float b) {
    float mx = fmaxf(a, b);
    return mx + __logf(__expf(a - mx) + __expf(b - mx));
}
__device__ __forceinline__ float lae3(float a, float b, float c) {
    float mx = fmaxf(fmaxf(a, b), c);
    return mx + __logf(__expf(a - mx) + __expf(b - mx) + __expf(c - mx));
}
__device__ __forceinline__ float tanh_fast(float x) {
    float ex = __expf(2.f * x);
    return 1.f - 2.f / (ex + 1.f);
}

// ---------------- pack fp32 (K x N) weight into bf16 MFMA B-fragment order.
__device__ __forceinline__ void pack_seg(const float* __restrict__ W, bf16_t* __restrict__ Wf,
                                         int e, int K32, int N)
{
    int j  = e & 7;
    int l  = (e >> 3) & 63;
    int kk = (e >> 9) % K32;
    int nt = e / (K32 * 512);
    int v = nt * 16 + (l & 15);
    int k = kk * 32 + ((l >> 4) << 2) + (j & 3) + ((j >> 2) << 4);
    Wf[e] = (bf16_t)W[(size_t)k * N + v];
}

// ---- pack W_out into fp8 e4m3 (scaled x16), kk-PAIRED layout:
// u32 word e32: word=(e32&3), l, kkp, nt; byte offset = ((nt*10+kkp)*64+l)*16
// + word*4.  word>>1 = kk parity, (word&1)*4 = j base. k-map identical to A.
__device__ __forceinline__ void pack_out8(const float* __restrict__ W, unsigned* __restrict__ Wf8,
                                          int e32)
{
    int word = e32 & 3;
    int l    = (e32 >> 2) & 63;
    int kkp  = (e32 >> 8) % 10;
    int nt   = e32 / 2560;
    int v  = nt * 16 + (l & 15);
    int kk = kkp * 2 + (word >> 1);
    int jb = (word & 1) * 4;
    float f[4];
#pragma unroll
    for (int t = 0; t < 4; ++t) {
        int j = jb + t;
        int k = kk * 32 + ((l >> 4) << 2) + (j & 3) + ((j >> 2) << 4);
        f[t] = W[(size_t)k * VV + v] * 16.f;
    }
    unsigned r = __builtin_amdgcn_cvt_pk_fp8_f32(f[0], f[1], 0, false);
    r = __builtin_amdgcn_cvt_pk_fp8_f32(f[2], f[3], r, true);
    Wf8[e32] = r;
}

__global__ void pack_all(const float* __restrict__ Wout, const float* __restrict__ Wenc,
                         const float* __restrict__ Wpred, const float* __restrict__ Wctc,
                         unsigned* __restrict__ FOut8, bf16_t* __restrict__ FEnc,
                         bf16_t* __restrict__ FPred, bf16_t* __restrict__ FCtc)
{
    int e = blockIdx.x * 256 + threadIdx.x;
    if (e < 163840) { pack_out8(Wout, FOut8, e); return; }
    e -= 163840;
    if (e < 327680) { pack_seg(Wenc, FEnc, e, 16, 640); return; }
    e -= 327680;
    if (e < 409600) { pack_seg(Wpred, FPred, e, 20, 640); return; }
    e -= 409600;
    pack_seg(Wctc, FCtc, e, 16, 1024);
}

// ---------------- generic bf16 MFMA GEMM (small gemms) ---------------------
template<int K32, int L, bool LSE, int J>
__device__ void gemm_dev(const float* __restrict__ A, int M, int rowbase, int K,
                         const bf16_t* __restrict__ Wf, const float* __restrict__ bias,
                         float* __restrict__ C, float* __restrict__ lse_out, int N,
                         bf16_t* Atile, float (*ps)[8])
{
    const int tid = threadIdx.x;
#pragma unroll
    for (int it = 0; it < J * K32 / 8; ++it) {
        int fi = it * 512 + tid;
        int l = fi & 63, jk = fi >> 6;
        int j = jk / K32, kk = jk - j * K32;
        int row = rowbase + j * 16 + (l & 15);
        if (row > M - 1) row = M - 1;
        int c0 = kk * 32 + ((l >> 4) << 2);
        const float4 a0 = *(const float4*)&A[(size_t)row * K + c0];
        const float4 a1 = *(const float4*)&A[(size_t)row * K + c0 + 16];
        bf16x8 v;
        v[0] = (bf16_t)a0.x; v[1] = (bf16_t)a0.y; v[2] = (bf16_t)a0.z; v[3] = (bf16_t)a0.w;
        v[4] = (bf16_t)a1.x; v[5] = (bf16_t)a1.y; v[6] = (bf16_t)a1.z; v[7] = (bf16_t)a1.w;
        *(bf16x8*)&Atile[(size_t)fi * 8] = v;
    }
    __syncthreads();

    const int l = tid & 63, w = tid >> 6;
    const int lrow = l & 15, lhi = l >> 4;

    f32x4 acc[J][L];
#pragma unroll
    for (int j = 0; j < J; ++j)
#pragma unroll
        for (int li = 0; li < L; ++li) acc[j][li] = f32x4{0.f, 0.f, 0.f, 0.f};

    for (int kk = 0; kk < K32; ++kk) {
        bf16x8 a[J];
#pragma unroll
        for (int j = 0; j < J; ++j)
            a[j] = *(const bf16x8*)&Atile[(size_t)(((j * K32 + kk) * 64 + l) * 8)];
#pragma unroll
        for (int li = 0; li < L; ++li) {
            bf16x8 b = *(const bf16x8*)&Wf[(size_t)(((w * L + li) * K32 + kk) * 64 + l) * 8];
#pragma unroll
            for (int j = 0; j < J; ++j)
                acc[j][li] = __builtin_amdgcn_mfma_f32_16x16x32_bf16(a[j], b, acc[j][li], 0, 0, 0);
        }
    }

    float se[J][4];
    if (LSE) {
#pragma unroll
        for (int j = 0; j < J; ++j)
#pragma unroll
            for (int i = 0; i < 4; ++i) se[j][i] = 0.f;
    }
#pragma unroll
    for (int j = 0; j < J; ++j)
#pragma unroll
        for (int li = 0; li < L; ++li) {
            int col = (w * L + li) * 16 + lrow;
            float bv = bias ? bias[col] : 0.f;
#pragma unroll
            for (int i = 0; i < 4; ++i) {
                int grow = rowbase + 16 * j + lhi * 4 + i;
                float x = acc[j][li][i] + bv;
                if (grow < M) C[(size_t)grow * N + col] = x;
                if (LSE) se[j][i] += __expf(x);
            }
        }
    if (LSE) {
#pragma unroll
        for (int d = 1; d < 16; d <<= 1)
#pragma unroll
            for (int j = 0; j < J; ++j)
#pragma unroll
                for (int i = 0; i < 4; ++i) se[j][i] += __shfl_xor(se[j][i], d);
        if (lrow == 0) {
#pragma unroll
            for (int j = 0; j < J; ++j)
#pragma unroll
                for (int i = 0; i < 4; ++i) ps[16 * j + lhi * 4 + i][w] = se[j][i];
        }
        __syncthreads();
        if (tid < J * 16) {
            float s = 0.f;
#pragma unroll
            for (int w0 = 0; w0 < 8; ++w0) s += ps[tid][w0];
            int grow = rowbase + tid;
            if (grow < M) lse_out[grow] = __logf(s);
        }
    }
}

__global__ __launch_bounds__(512)
void mfma_gemm3(const float* __restrict__ x_enc, const float* __restrict__ x_dec,
                const bf16_t* __restrict__ FEnc, const bf16_t* __restrict__ FPred,
                const bf16_t* __restrict__ FCtc, const float* __restrict__ b_ctc,
                float* __restrict__ enc_proj, float* __restrict__ pred_proj,
                float* __restrict__ ctc_logits, float* __restrict__ ctc_lse)
{
    __shared__ bf16_t Atile[40960];
    __shared__ float ps[64][8];
    int blk = blockIdx.x;
    if (blk < 13)
        gemm_dev<16, 5, false, 4>(x_enc, 800, blk * 64, 512, FEnc, nullptr, enc_proj, nullptr, 640, Atile, ps);
    else if (blk < 17)
        gemm_dev<20, 5, false, 4>(x_dec, 204, (blk - 13) * 64, 640, FPred, nullptr, pred_proj, nullptr, 640, Atile, ps);
    else
        gemm_dev<16, 8, true, 4>(x_enc, 800, (blk - 17) * 64, 512, FCtc, b_ctc, ctc_logits, ctc_lse, 1024, Atile, ps);
}

// ---------------- fused joint build + fp8 MFMA GEMM + row-LSE + gather -----
// A tile 64x640 fp8 in LDS (40KB), kk-paired fragments: one ds_read_b128 /
// one dwordx4 B-load feeds TWO K-steps (64 MFMA per 12 mem-insts).
__global__ __launch_bounds__(512)
void joint_gemm(const float* __restrict__ enc,   // (800,640)
                const float* __restrict__ pred,  // (204,640)
                const float* __restrict__ bj,    // (640)
                const unsigned* __restrict__ Wf8,// packed fp8 (x16 scale)
                const float* __restrict__ bo,    // (1024)
                const int* __restrict__ target,  // (4,50)
                float* __restrict__ blank_buf, float* __restrict__ emit_buf)
{
    __shared__ __align__(16) char smbuf[40960];
    char* Afrag8 = smbuf;
    const int tid = threadIdx.x;
    const int blk = blockIdx.x;

    const int l = tid & 63, w = tid >> 6;
    const int lrow = l & 15, lhi = l >> 4;

    // build tanh(enc+pred+bj) as fp8, kk-paired chunks of 16B.
    // chunk c = (j*10+kkp)*64 + l ; 2560 chunks / 512 thr = 5 iters.
#pragma unroll
    for (int it = 0; it < 5; ++it) {
        int c = it * 512 + tid;
        int ll = c & 63, jk = c >> 6;
        int j = jk / 10, kkp = jk - j * 10;
        int row = j * 16 + (ll & 15);
        int r = blk * 64 + row; if (r > RTOT - 1) r = RTOT - 1;
        int b = r / (TT * U1); int rem = r - b * (TT * U1);
        int t = rem / U1;      int u = rem - t * U1;
        const float* erow = enc + (size_t)(b * TT + t) * HH;
        const float* prow = pred + (size_t)(b * U1 + u) * HH;
        int cb = kkp * 64 + ((ll >> 4) << 2);
        float f[16];
#pragma unroll
        for (int s = 0; s < 4; ++s) {
            int off = cb + s * 16;
            const float4 e4 = *(const float4*)&erow[off];
            const float4 p4 = *(const float4*)&prow[off];
            const float4 q4 = *(const float4*)&bj[off];
            f[s * 4 + 0] = tanh_fast(e4.x + p4.x + q4.x);
            f[s * 4 + 1] = tanh_fast(e4.y + p4.y + q4.y);
            f[s * 4 + 2] = tanh_fast(e4.z + p4.z + q4.z);
            f[s * 4 + 3] = tanh_fast(e4.w + p4.w + q4.w);
        }
        uint4 v;
        unsigned r0 = __builtin_amdgcn_cvt_pk_fp8_f32(f[0], f[1], 0, false);
        v.x = __builtin_amdgcn_cvt_pk_fp8_f32(f[2], f[3], r0, true);
        r0 = __builtin_amdgcn_cvt_pk_fp8_f32(f[4], f[5], 0, false);
        v.y = __builtin_amdgcn_cvt_pk_fp8_f32(f[6], f[7], r0, true);
        r0 = __builtin_amdgcn_cvt_pk_fp8_f32(f[8], f[9], 0, false);
        v.z = __builtin_amdgcn_cvt_pk_fp8_f32(f[10], f[11], r0, true);
        r0 = __builtin_amdgcn_cvt_pk_fp8_f32(f[12], f[13], 0, false);
        v.w = __builtin_amdgcn_cvt_pk_fp8_f32(f[14], f[15], r0, true);
        *(uint4*)&Afrag8[(size_t)c * 16] = v;
    }
    __syncthreads();

    f32x4 acc[4][8];
#pragma unroll
    for (int j = 0; j < 4; ++j)
#pragma unroll
        for (int li = 0; li < 8; ++li) acc[j][li] = f32x4{0.f, 0.f, 0.f, 0.f};

    const char* Bp8 = (const char*)Wf8 + (size_t)(w * 8) * 10240 + (size_t)l * 16;

    // K loop over kk-pairs, rotated per block (L2 decorrelation), two linear
    // segments for strength-reduced addressing.
    const int rot = blk % 10;
    auto kstep = [&](int kkp) {
        long2_t a[4];
#pragma unroll
        for (int j = 0; j < 4; ++j)
            a[j] = *(const long2_t*)&Afrag8[(size_t)(((j * 10 + kkp) * 64 + l) * 16)];
#pragma unroll
        for (int li = 0; li < 8; ++li) {
            long2_t b = *(const long2_t*)(Bp8 + (size_t)li * 10240 + (size_t)kkp * 1024);
#pragma unroll
            for (int j = 0; j < 4; ++j)
                acc[j][li] = __builtin_amdgcn_mfma_f32_16x16x32_fp8_fp8(a[j][0], b[0], acc[j][li], 0, 0, 0);
#pragma unroll
            for (int j = 0; j < 4; ++j)
                acc[j][li] = __builtin_amdgcn_mfma_f32_16x16x32_fp8_fp8(a[j][1], b[1], acc[j][li], 0, 0, 0);
        }
    };
    for (int kkp = rot; kkp < 10; ++kkp) kstep(kkp);
    for (int kkp = 0; kkp < rot; ++kkp) kstep(kkp);

    // per-thread target tokens for the 16 owned rows
    int tg[4][4];
#pragma unroll
    for (int j = 0; j < 4; ++j)
#pragma unroll
        for (int i = 0; i < 4; ++i) {
            int r = blk * 64 + 16 * j + lhi * 4 + i; if (r > RTOT - 1) r = RTOT - 1;
            int b = r / (TT * U1); int rem = r - b * (TT * U1);
            int u = rem % U1;
            tg[j][i] = (u < UU) ? target[b * UU + u] : -1;
        }

    float se[4][4], ee[4][4], bbv[4][4];
#pragma unroll
    for (int j = 0; j < 4; ++j)
#pragma unroll
        for (int i = 0; i < 4; ++i) { se[j][i] = 0.f; ee[j][i] = NEGV; bbv[j][i] = NEGV; }

#pragma unroll
    for (int li = 0; li < 8; ++li) {
        int col = (w * 8 + li) * 16 + lrow;
        float bv = bo[col];
#pragma unroll
        for (int j = 0; j < 4; ++j)
#pragma unroll
            for (int i = 0; i < 4; ++i) {
                float x = acc[j][li][i] * 0.0625f + bv;   // undo x16 W scale
                se[j][i] += __expf(x);
                if (col == tg[j][i]) ee[j][i] = x;
            }
    }
    // blank col 1023 lives only at w==7, li==7, lrow==15 (uniform guard)
    if (w == 7) {
        float bv = bo[1023];
#pragma unroll
        for (int j = 0; j < 4; ++j)
#pragma unroll
            for (int i = 0; i < 4; ++i) {
                float x = acc[j][7][i] * 0.0625f + bv;
                if (lrow == 15) bbv[j][i] = x;
            }
    }
#pragma unroll
    for (int d = 1; d < 16; d <<= 1)
#pragma unroll
        for (int j = 0; j < 4; ++j)
#pragma unroll
            for (int i = 0; i < 4; ++i) {
                se[j][i] += __shfl_xor(se[j][i], d);
                ee[j][i] = fmaxf(ee[j][i], __shfl_xor(ee[j][i], d));
                bbv[j][i] = fmaxf(bbv[j][i], __shfl_xor(bbv[j][i], d));
            }

    // Afrag8 dead; overlay cross-wave reduction arrays [64][8].
    __syncthreads();
    float (*ps)[8] = (float (*)[8])(smbuf);
    float (*pe)[8] = (float (*)[8])(smbuf + 2048);
    float (*pb)[8] = (float (*)[8])(smbuf + 4096);
    if (lrow == 0) {
#pragma unroll
        for (int j = 0; j < 4; ++j)
#pragma unroll
            for (int i = 0; i < 4; ++i) {
                int r = 16 * j + lhi * 4 + i;
                ps[r][w] = se[j][i]; pe[r][w] = ee[j][i]; pb[r][w] = bbv[j][i];
            }
    }
    __syncthreads();
    if (tid < 64) {
        float s = 0.f, e = NEGV, bq = NEGV;
#pragma unroll
        for (int w0 = 0; w0 < 8; ++w0) {
            s += ps[tid][w0];
            e = fmaxf(e, pe[tid][w0]);
            bq = fmaxf(bq, pb[tid][w0]);
        }
        float lse = __logf(s);
        int gid = blk * 64 + tid;
        if (gid < RTOT) {
            blank_buf[gid] = bq - lse;
            emit_buf[gid]  = e - lse;
        }
    }
}

// ---------------- fused DPs: blocks 0-3 RNNT (wavefront), 4-7 CTC ----------
__global__ void dp_fused(const float* __restrict__ blank_buf, const float* __restrict__ emit_buf,
                         const float* __restrict__ ctc_logits, const float* __restrict__ ctc_lse,
                         const int* __restrict__ target, const int* __restrict__ frame_len,
                         const int* __restrict__ tgt_len,
                         float* __restrict__ loss_rnnt, float* __restrict__ loss_ctc)
{
    __shared__ float sm[20864];
    const int bid = blockIdx.x;
    const int u = threadIdx.x;   // 64

    if (bid < 4) {
        const int b = bid;
        float2* pk = (float2*)sm;    // [200][52]
        for (int i = u; i < TT * U1; i += 64) {
            int t = i / U1, uu = i - t * U1;
            float bl = blank_buf[(b * TT + t) * U1 + uu];
            float em = emit_buf[(b * TT + t) * U1 + uu];
            pk[t * 52 + uu] = make_float2(bl, em);
        }
        __syncthreads();
        const int fl = frame_len[b], tl = tgt_len[b];
        float A = (u == 0) ? 0.f : NEGV;
        if (fl == 1 && tl == 0 && u == 0) loss_rnnt[b] = -(A + pk[0].x);
        for (int d = 1; d <= TT + U1 - 2; ++d) {
            int x = d - 1 - u;
            int xc = min(max(x, 0), TT - 1);
            int uc = min(u, 51);
            float2 be = pk[xc * 52 + uc];
            float vshare = A + be.y;
            float left = __shfl_up(vshare, 1);
            if (u == 0) left = NEGV;
            int t_new = d - u;
            if (u < U1 && t_new >= 0 && t_new < TT) {
                float up = (t_new >= 1) ? (A + be.x) : NEGV;
                A = lae(up, left);
                if (t_new == fl - 1 && u == tl)
                    loss_rnnt[b] = -(A + pk[t_new * 52 + u].x);
            }
        }
    } else {
        const int b = bid - 4;
        float* lpE  = sm;
        float* lseB = sm + 200;
        float (*lpO)[52] = (float(*)[52])(sm + 400);
        for (int idx = u; idx < 200; idx += 64) {
            int bt = b * 200 + idx;
            float ls = ctc_lse[bt];
            lseB[idx] = ls;
            lpE[idx] = ctc_logits[(size_t)bt * VV + (VV - 1)] - ls;
        }
        for (int idx = u; idx < 200 * 50; idx += 64) {
            int t = idx / 50, uu = idx - t * 50;
            int tok = target[b * UU + uu];
            lpO[t][uu] = ctc_logits[(size_t)(b * 200 + t) * VV + tok];
        }
        __syncthreads();
        const int fl = frame_len[b], tl = tgt_len[b];
        bool skip = false;
        if (u >= 1 && u < UU) skip = (target[b * UU + u] != target[b * UU + u - 1]);

        float old_e = (u == 0) ? lpE[0] : NEGV;
        float old_o = (u == 0) ? (lpO[0][0] - lseB[0]) : NEGV;
        if (fl == 1 && u == 0) {
            float a_last = __shfl(old_e, tl);
            float a_prev = __shfl(old_o, tl - 1);
            loss_ctc[b] = -lae(a_last, a_prev);
        }
        for (int t = 1; t < 200; ++t) {
            float prev_o = __shfl_up(old_o, 1);
            if (u == 0) prev_o = NEGV;
            float lp_e = lpE[t];
            float lp_o = (u < UU) ? (lpO[t][u] - lseB[t]) : NEGV;
            float ne = lp_e + lae(old_e, prev_o);
            float no = lp_o + lae3(old_o, old_e, skip ? prev_o : NEGV);
            if (u > 50) ne = NEGV;
            if (u >= 50) no = NEGV;
            old_e = ne; old_o = no;
            if (t == fl - 1) {
                float a_last = __shfl(old_e, tl);
                float a_prev = __shfl(old_o, tl - 1);
                if (u == 0) loss_ctc[b] = -lae(a_last, a_prev);
            }
        }
    }
}

// ---------------- final combine -------------------------------------------
__global__ void combine(const float* __restrict__ lr, const float* __restrict__ lc,
                        float* __restrict__ out)
{
    float r = 0.25f * (lr[0] + lr[1] + lr[2] + lr[3]);
    float c = 0.25f * (lc[0] + lc[1] + lc[2] + lc[3]);
    out[0] = r + 0.3f * c;
}

extern "C" void kernel_launch(void* const* d_in, const int* in_sizes, int n_in,
                              void* d_out, int out_size, void* d_ws, size_t ws_size,
                              hipStream_t stream)
{
    const float* x_enc   = (const float*)d_in[0];
    const float* x_dec   = (const float*)d_in[1];
    const int*   target  = (const int*)d_in[2];
    const int*   frame_l = (const int*)d_in[3];
    const int*   tgt_l   = (const int*)d_in[4];
    const float* W_ctc   = (const float*)d_in[5];
    const float* b_ctc   = (const float*)d_in[6];
    const float* W_enc   = (const float*)d_in[7];
    const float* W_pred  = (const float*)d_in[8];
    const float* b_joint = (const float*)d_in[9];
    const float* W_out   = (const float*)d_in[10];
    const float* b_out   = (const float*)d_in[11];
    float* out = (float*)d_out;

    float* wsf        = (float*)d_ws;
    float* enc_proj   = wsf;                       // 512000
    float* pred_proj  = wsf + 512000;              // 130560
    float* ctc_logits = wsf + 642560;              // 819200
    float* ctc_lse    = wsf + 1461760;             // 832
    float* blank_buf  = wsf + 1462592;             // 40832
    float* emit_buf   = wsf + 1503424;             // 40832
    float* loss_rnnt  = wsf + 1544256;             // 4
    float* loss_ctc   = wsf + 1544260;             // 4 (+pad to 1544272)
    unsigned* FOut8 = (unsigned*)(wsf + 1544272);  // 163840 u32 (655360 B fp8)
    bf16_t* FEnc  = (bf16_t*)(wsf + 1708112);      // 327680 bf16
    bf16_t* FPred = (bf16_t*)(wsf + 1871952);      // 409600 bf16
    bf16_t* FCtc  = (bf16_t*)(wsf + 2076752);      // 524288 bf16

    pack_all<<<5568, 256, 0, stream>>>(W_out, W_enc, W_pred, W_ctc, FOut8, FEnc, FPred, FCtc);
    mfma_gemm3<<<30, 512, 0, stream>>>(x_enc, x_dec, FEnc, FPred, FCtc, b_ctc,
                                       enc_proj, pred_proj, ctc_logits, ctc_lse);
    joint_gemm<<<RPAD / 64, 512, 0, stream>>>(enc_proj, pred_proj, b_joint, FOut8, b_out,
                                              target, blank_buf, emit_buf);
    dp_fused<<<8, 64, 0, stream>>>(blank_buf, emit_buf, ctc_logits, ctc_lse,
                                   target, frame_l, tgt_l, loss_rnnt, loss_ctc);
    combine<<<1, 1, 0, stream>>>(loss_rnnt, loss_ctc, out);
}

// Round 11
// 166.197 us; speedup vs baseline: 3.4108x; 1.2708x over previous
//
#include <hip/hip_runtime.h>
#include <hip/hip_bf16.h>

typedef __bf16 bf16_t;
typedef __attribute__((ext_vector_type(8))) __bf16 bf16x8;
typedef __attribute__((ext_vector_type(4))) float f32x4;
typedef __attribute__((ext_vector_type(2))) long long2_t;

#define NEGV (-1e30f)

// Problem constants
#define BB 4
#define TT 200
#define UU 50
#define U1 51
#define VV 1024
#define DD 512
#define HH 640
#define RTOT (BB*TT*U1)      // 40800
#define RPAD 40832           // 638*64
#define SS 101

__device__ __forceinline__ float lae(float a, float b) {
    float mx = fmaxf(a, b);
    return mx + __logf(__expf(a - mx) + __expf(b - mx));
}
__device__ __forceinline__ float lae3(float a, float b, float c) {
    float mx = fmaxf(fmaxf(a, b), c);
    return mx + __logf(__expf(a - mx) + __expf(b - mx) + __expf(c - mx));
}
__device__ __forceinline__ float tanh_fast(float x) {
    float ex = __expf(2.f * x);
    return 1.f - 2.f / (ex + 1.f);
}

// ---------------- pack fp32 (K x N) weight into bf16 MFMA B-fragment order.
__device__ __forceinline__ void pack_seg(const float* __restrict__ W, bf16_t* __restrict__ Wf,
                                         int e, int K32, int N)
{
    int j  = e & 7;
    int l  = (e >> 3) & 63;
    int kk = (e >> 9) % K32;
    int nt = e / (K32 * 512);
    int v = nt * 16 + (l & 15);
    int k = kk * 32 + ((l >> 4) << 2) + (j & 3) + ((j >> 2) << 4);
    Wf[e] = (bf16_t)W[(size_t)k * N + v];
}

// ---- pack W_out into fp8 e4m3 (scaled x16), kk-PAIRED layout.
__device__ __forceinline__ void pack_out8(const float* __restrict__ W, unsigned* __restrict__ Wf8,
                                          int e32)
{
    int word = e32 & 3;
    int l    = (e32 >> 2) & 63;
    int kkp  = (e32 >> 8) % 10;
    int nt   = e32 / 2560;
    int v  = nt * 16 + (l & 15);
    int kk = kkp * 2 + (word >> 1);
    int jb = (word & 1) * 4;
    float f[4];
#pragma unroll
    for (int t = 0; t < 4; ++t) {
        int j = jb + t;
        int k = kk * 32 + ((l >> 4) << 2) + (j & 3) + ((j >> 2) << 4);
        f[t] = W[(size_t)k * VV + v] * 16.f;
    }
    unsigned r = __builtin_amdgcn_cvt_pk_fp8_f32(f[0], f[1], 0, false);
    r = __builtin_amdgcn_cvt_pk_fp8_f32(f[2], f[3], r, true);
    Wf8[e32] = r;
}

__global__ void pack_all(const float* __restrict__ Wout, const float* __restrict__ Wenc,
                         const float* __restrict__ Wpred, const float* __restrict__ Wctc,
                         unsigned* __restrict__ FOut8, bf16_t* __restrict__ FEnc,
                         bf16_t* __restrict__ FPred, bf16_t* __restrict__ FCtc)
{
    int e = blockIdx.x * 256 + threadIdx.x;
    if (e < 163840) { pack_out8(Wout, FOut8, e); return; }
    e -= 163840;
    if (e < 327680) { pack_seg(Wenc, FEnc, e, 16, 640); return; }
    e -= 327680;
    if (e < 409600) { pack_seg(Wpred, FPred, e, 20, 640); return; }
    e -= 409600;
    pack_seg(Wctc, FCtc, e, 16, 1024);
}

// ---------------- generic bf16 MFMA GEMM (small gemms) ---------------------
template<int K32, int L, bool LSE, int J>
__device__ void gemm_dev(const float* __restrict__ A, int M, int rowbase, int K,
                         const bf16_t* __restrict__ Wf, const float* __restrict__ bias,
                         float* __restrict__ C, float* __restrict__ lse_out, int N,
                         bf16_t* Atile, float (*ps)[8])
{
    const int tid = threadIdx.x;
#pragma unroll
    for (int it = 0; it < J * K32 / 8; ++it) {
        int fi = it * 512 + tid;
        int l = fi & 63, jk = fi >> 6;
        int j = jk / K32, kk = jk - j * K32;
        int row = rowbase + j * 16 + (l & 15);
        if (row > M - 1) row = M - 1;
        int c0 = kk * 32 + ((l >> 4) << 2);
        const float4 a0 = *(const float4*)&A[(size_t)row * K + c0];
        const float4 a1 = *(const float4*)&A[(size_t)row * K + c0 + 16];
        bf16x8 v;
        v[0] = (bf16_t)a0.x; v[1] = (bf16_t)a0.y; v[2] = (bf16_t)a0.z; v[3] = (bf16_t)a0.w;
        v[4] = (bf16_t)a1.x; v[5] = (bf16_t)a1.y; v[6] = (bf16_t)a1.z; v[7] = (bf16_t)a1.w;
        *(bf16x8*)&Atile[(size_t)fi * 8] = v;
    }
    __syncthreads();

    const int l = tid & 63, w = tid >> 6;
    const int lrow = l & 15, lhi = l >> 4;

    f32x4 acc[J][L];
#pragma unroll
    for (int j = 0; j < J; ++j)
#pragma unroll
        for (int li = 0; li < L; ++li) acc[j][li] = f32x4{0.f, 0.f, 0.f, 0.f};

    for (int kk = 0; kk < K32; ++kk) {
        bf16x8 a[J];
#pragma unroll
        for (int j = 0; j < J; ++j)
            a[j] = *(const bf16x8*)&Atile[(size_t)(((j * K32 + kk) * 64 + l) * 8)];
#pragma unroll
        for (int li = 0; li < L; ++li) {
            bf16x8 b = *(const bf16x8*)&Wf[(size_t)(((w * L + li) * K32 + kk) * 64 + l) * 8];
#pragma unroll
            for (int j = 0; j < J; ++j)
                acc[j][li] = __builtin_amdgcn_mfma_f32_16x16x32_bf16(a[j], b, acc[j][li], 0, 0, 0);
        }
    }

    float se[J][4];
    if (LSE) {
#pragma unroll
        for (int j = 0; j < J; ++j)
#pragma unroll
            for (int i = 0; i < 4; ++i) se[j][i] = 0.f;
    }
#pragma unroll
    for (int j = 0; j < J; ++j)
#pragma unroll
        for (int li = 0; li < L; ++li) {
            int col = (w * L + li) * 16 + lrow;
            float bv = bias ? bias[col] : 0.f;
#pragma unroll
            for (int i = 0; i < 4; ++i) {
                int grow = rowbase + 16 * j + lhi * 4 + i;
                float x = acc[j][li][i] + bv;
                if (grow < M) C[(size_t)grow * N + col] = x;
                if (LSE) se[j][i] += __expf(x);
            }
        }
    if (LSE) {
#pragma unroll
        for (int d = 1; d < 16; d <<= 1)
#pragma unroll
            for (int j = 0; j < J; ++j)
#pragma unroll
                for (int i = 0; i < 4; ++i) se[j][i] += __shfl_xor(se[j][i], d);
        if (lrow == 0) {
#pragma unroll
            for (int j = 0; j < J; ++j)
#pragma unroll
                for (int i = 0; i < 4; ++i) ps[16 * j + lhi * 4 + i][w] = se[j][i];
        }
        __syncthreads();
        if (tid < J * 16) {
            float s = 0.f;
#pragma unroll
            for (int w0 = 0; w0 < 8; ++w0) s += ps[tid][w0];
            int grow = rowbase + tid;
            if (grow < M) lse_out[grow] = __logf(s);
        }
    }
}

__global__ __launch_bounds__(512)
void mfma_gemm3(const float* __restrict__ x_enc, const float* __restrict__ x_dec,
                const bf16_t* __restrict__ FEnc, const bf16_t* __restrict__ FPred,
                const bf16_t* __restrict__ FCtc, const float* __restrict__ b_ctc,
                float* __restrict__ enc_proj, float* __restrict__ pred_proj,
                float* __restrict__ ctc_logits, float* __restrict__ ctc_lse)
{
    __shared__ bf16_t Atile[40960];
    __shared__ float ps[64][8];
    int blk = blockIdx.x;
    if (blk < 13)
        gemm_dev<16, 5, false, 4>(x_enc, 800, blk * 64, 512, FEnc, nullptr, enc_proj, nullptr, 640, Atile, ps);
    else if (blk < 17)
        gemm_dev<20, 5, false, 4>(x_dec, 204, (blk - 13) * 64, 640, FPred, nullptr, pred_proj, nullptr, 640, Atile, ps);
    else
        gemm_dev<16, 8, true, 4>(x_enc, 800, (blk - 17) * 64, 512, FCtc, b_ctc, ctc_logits, ctc_lse, 1024, Atile, ps);
}

// ---------------- fused joint build + fp8 MFMA GEMM + row-LSE + gather -----
__global__ __launch_bounds__(512)
void joint_gemm(const float* __restrict__ enc,   // (800,640)
                const float* __restrict__ pred,  // (204,640)
                const float* __restrict__ bj,    // (640)
                const unsigned* __restrict__ Wf8,// packed fp8 (x16 scale)
                const float* __restrict__ bo,    // (1024)
                const int* __restrict__ target,  // (4,50)
                float* __restrict__ blank_buf, float* __restrict__ emit_buf)
{
    __shared__ __align__(16) char smbuf[40960];
    char* Afrag8 = smbuf;
    const int tid = threadIdx.x;
    const int blk = blockIdx.x;

    const int l = tid & 63, w = tid >> 6;
    const int lrow = l & 15, lhi = l >> 4;

#pragma unroll
    for (int it = 0; it < 5; ++it) {
        int c = it * 512 + tid;
        int ll = c & 63, jk = c >> 6;
        int j = jk / 10, kkp = jk - j * 10;
        int row = j * 16 + (ll & 15);
        int r = blk * 64 + row; if (r > RTOT - 1) r = RTOT - 1;
        int b = r / (TT * U1); int rem = r - b * (TT * U1);
        int t = rem / U1;      int u = rem - t * U1;
        const float* erow = enc + (size_t)(b * TT + t) * HH;
        const float* prow = pred + (size_t)(b * U1 + u) * HH;
        int cb = kkp * 64 + ((ll >> 4) << 2);
        float f[16];
#pragma unroll
        for (int s = 0; s < 4; ++s) {
            int off = cb + s * 16;
            const float4 e4 = *(const float4*)&erow[off];
            const float4 p4 = *(const float4*)&prow[off];
            const float4 q4 = *(const float4*)&bj[off];
            f[s * 4 + 0] = tanh_fast(e4.x + p4.x + q4.x);
            f[s * 4 + 1] = tanh_fast(e4.y + p4.y + q4.y);
            f[s * 4 + 2] = tanh_fast(e4.z + p4.z + q4.z);
            f[s * 4 + 3] = tanh_fast(e4.w + p4.w + q4.w);
        }
        uint4 v;
        unsigned r0 = __builtin_amdgcn_cvt_pk_fp8_f32(f[0], f[1], 0, false);
        v.x = __builtin_amdgcn_cvt_pk_fp8_f32(f[2], f[3], r0, true);
        r0 = __builtin_amdgcn_cvt_pk_fp8_f32(f[4], f[5], 0, false);
        v.y = __builtin_amdgcn_cvt_pk_fp8_f32(f[6], f[7], r0, true);
        r0 = __builtin_amdgcn_cvt_pk_fp8_f32(f[8], f[9], 0, false);
        v.z = __builtin_amdgcn_cvt_pk_fp8_f32(f[10], f[11], r0, true);
        r0 = __builtin_amdgcn_cvt_pk_fp8_f32(f[12], f[13], 0, false);
        v.w = __builtin_amdgcn_cvt_pk_fp8_f32(f[14], f[15], r0, true);
        *(uint4*)&Afrag8[(size_t)c * 16] = v;
    }
    __syncthreads();

    f32x4 acc[4][8];
#pragma unroll
    for (int j = 0; j < 4; ++j)
#pragma unroll
        for (int li = 0; li < 8; ++li) acc[j][li] = f32x4{0.f, 0.f, 0.f, 0.f};

    const char* Bp8 = (const char*)Wf8 + (size_t)(w * 8) * 10240 + (size_t)l * 16;

    const int rot = blk % 10;
    auto kstep = [&](int kkp) {
        long2_t a[4];
#pragma unroll
        for (int j = 0; j < 4; ++j)
            a[j] = *(const long2_t*)&Afrag8[(size_t)(((j * 10 + kkp) * 64 + l) * 16)];
#pragma unroll
        for (int li = 0; li < 8; ++li) {
            long2_t b = *(const long2_t*)(Bp8 + (size_t)li * 10240 + (size_t)kkp * 1024);
#pragma unroll
            for (int j = 0; j < 4; ++j)
                acc[j][li] = __builtin_amdgcn_mfma_f32_16x16x32_fp8_fp8(a[j][0], b[0], acc[j][li], 0, 0, 0);
#pragma unroll
            for (int j = 0; j < 4; ++j)
                acc[j][li] = __builtin_amdgcn_mfma_f32_16x16x32_fp8_fp8(a[j][1], b[1], acc[j][li], 0, 0, 0);
        }
    };
    for (int kkp = rot; kkp < 10; ++kkp) kstep(kkp);
    for (int kkp = 0; kkp < rot; ++kkp) kstep(kkp);

    int tg[4][4];
#pragma unroll
    for (int j = 0; j < 4; ++j)
#pragma unroll
        for (int i = 0; i < 4; ++i) {
            int r = blk * 64 + 16 * j + lhi * 4 + i; if (r > RTOT - 1) r = RTOT - 1;
            int b = r / (TT * U1); int rem = r - b * (TT * U1);
            int u = rem % U1;
            tg[j][i] = (u < UU) ? target[b * UU + u] : -1;
        }

    float se[4][4], ee[4][4], bbv[4][4];
#pragma unroll
    for (int j = 0; j < 4; ++j)
#pragma unroll
        for (int i = 0; i < 4; ++i) { se[j][i] = 0.f; ee[j][i] = NEGV; bbv[j][i] = NEGV; }

#pragma unroll
    for (int li = 0; li < 8; ++li) {
        int col = (w * 8 + li) * 16 + lrow;
        float bv = bo[col];
#pragma unroll
        for (int j = 0; j < 4; ++j)
#pragma unroll
            for (int i = 0; i < 4; ++i) {
                float x = acc[j][li][i] * 0.0625f + bv;   // undo x16 W scale
                se[j][i] += __expf(x);
                if (col == tg[j][i]) ee[j][i] = x;
            }
    }
    if (w == 7) {
        float bv = bo[1023];
#pragma unroll
        for (int j = 0; j < 4; ++j)
#pragma unroll
            for (int i = 0; i < 4; ++i) {
                float x = acc[j][7][i] * 0.0625f + bv;
                if (lrow == 15) bbv[j][i] = x;
            }
    }
#pragma unroll
    for (int d = 1; d < 16; d <<= 1)
#pragma unroll
        for (int j = 0; j < 4; ++j)
#pragma unroll
            for (int i = 0; i < 4; ++i) {
                se[j][i] += __shfl_xor(se[j][i], d);
                ee[j][i] = fmaxf(ee[j][i], __shfl_xor(ee[j][i], d));
                bbv[j][i] = fmaxf(bbv[j][i], __shfl_xor(bbv[j][i], d));
            }

    __syncthreads();
    float (*ps)[8] = (float (*)[8])(smbuf);
    float (*pe)[8] = (float (*)[8])(smbuf + 2048);
    float (*pb)[8] = (float (*)[8])(smbuf + 4096);
    if (lrow == 0) {
#pragma unroll
        for (int j = 0; j < 4; ++j)
#pragma unroll
            for (int i = 0; i < 4; ++i) {
                int r = 16 * j + lhi * 4 + i;
                ps[r][w] = se[j][i]; pe[r][w] = ee[j][i]; pb[r][w] = bbv[j][i];
            }
    }
    __syncthreads();
    if (tid < 64) {
        float s = 0.f, e = NEGV, bq = NEGV;
#pragma unroll
        for (int w0 = 0; w0 < 8; ++w0) {
            s += ps[tid][w0];
            e = fmaxf(e, pe[tid][w0]);
            bq = fmaxf(bq, pb[tid][w0]);
        }
        float lse = __logf(s);
        int gid = blk * 64 + tid;
        if (gid < RTOT) {
            blank_buf[gid] = bq - lse;
            emit_buf[gid]  = e - lse;
        }
    }
}

// ---------------- fused DPs: blocks 0-3 RNNT (wavefront), 4-7 CTC ----------
// Latency-optimized: [u][t] LDS layout, 8-step unroll with batched LDS
// reads off the critical chain, branchless harvest via cndmask registers.
__global__ __launch_bounds__(256)
void dp_fused(const float* __restrict__ blank_buf, const float* __restrict__ emit_buf,
              const float* __restrict__ ctc_logits, const float* __restrict__ ctc_lse,
              const int* __restrict__ target, const int* __restrict__ frame_len,
              const int* __restrict__ tgt_len,
              float* __restrict__ loss_rnnt, float* __restrict__ loss_ctc)
{
    __shared__ __align__(16) float sm[28416];   // 111 KB (RNNT pk[64][217] f2)
    const int bid = blockIdx.x;
    const int tid = threadIdx.x;

    if (bid < 4) {
        const int b = bid;
        float2* pk = (float2*)sm;               // [64][217]; t stored at t+8
        for (int i = tid; i < TT * U1; i += 256) {
            int t = i / U1, uu = i - t * U1;
            float bl = blank_buf[(b * TT + t) * U1 + uu];
            float em = emit_buf[(b * TT + t) * U1 + uu];
            pk[uu * 217 + t + 8] = make_float2(bl, em);
        }
        __syncthreads();
        if (tid >= 64) return;
        const int u = tid;
        const int fl = frame_len[b], tl = tgt_len[b];
        const int dh = fl - 1 + tl;             // harvest diagonal
        const bool isTL = (u == tl);
        const bool act = (u < U1);
        float A = (u == 0) ? 0.f : NEGV;
        float Asave = (dh == 0 && isTL) ? A : NEGV;
        const float2* prow = pk + u * 217;

        for (int d0 = 1; d0 <= 249; d0 += 8) {
            int tb = d0 - 1 - u;                // t of buf[0]
            int tc = tb; if (tc < -8) tc = -8; if (tc > 200) tc = 200;
            float2 buf[8];
#pragma unroll
            for (int s = 0; s < 8; ++s) buf[s] = prow[tc + 8 + s];
#pragma unroll
            for (int s = 0; s < 8; ++s) {
                int d = d0 + s;
                int t_new = d - u;
                float2 be = buf[s];
                float vshare = A + be.y;
                float left = __shfl_up(vshare, 1);
                if (u == 0) left = NEGV;
                float up = (t_new >= 1) ? (A + be.x) : NEGV;
                float Anew = lae(up, left);
                bool valid = act && (t_new >= 0) && (t_new < TT);
                A = valid ? Anew : A;
                Asave = (isTL && d == dh) ? A : Asave;
            }
        }
        if (isTL && act) {
            float bl = prow[(fl - 1) + 8].x;
            loss_rnnt[b] = -(Asave + bl);
        }
    } else {
        const int b = bid - 4;
        float* lpE = sm;                         // [208] blank-state lp (norm)
        float* lpO = sm + 208;                   // [50][209] token lp (norm)
        for (int i = tid; i < TT; i += 256) {
            int bt = b * TT + i;
            lpE[i] = ctc_logits[(size_t)bt * VV + (VV - 1)] - ctc_lse[bt];
        }
        for (int i = tid; i < TT * UU; i += 256) {
            int t = i / UU, uu = i - t * UU;
            int bt = b * TT + t;
            lpO[uu * 209 + t] = ctc_logits[(size_t)bt * VV + target[b * UU + uu]] - ctc_lse[bt];
        }
        __syncthreads();
        if (tid >= 64) return;
        const int u = tid;
        const int fl = frame_len[b], tl = tgt_len[b];
        const bool acte = (u <= 50);
        const bool acto = (u < 50);
        bool skip = (u >= 1 && u < UU) ? (target[b * UU + u] != target[b * UU + u - 1]) : false;
        const float* orow = lpO + u * 209;
        float old_e = (u == 0) ? lpE[0] : NEGV;
        float old_o = (u == 0) ? orow[0] : NEGV;
        float Esave = (fl == 1) ? old_e : NEGV;
        float Osave = (fl == 1) ? old_o : NEGV;

        for (int t0 = 1; t0 <= 193; t0 += 8) {
            float bo8[8], be8[8];
#pragma unroll
            for (int s = 0; s < 8; ++s) { bo8[s] = orow[t0 + s]; be8[s] = lpE[t0 + s]; }
#pragma unroll
            for (int s = 0; s < 8; ++s) {
                int t = t0 + s;
                float prev_o = __shfl_up(old_o, 1);
                if (u == 0) prev_o = NEGV;
                float ne = be8[s] + lae(old_e, prev_o);
                float no = bo8[s] + lae3(old_o, old_e, skip ? prev_o : NEGV);
                old_e = acte ? ne : NEGV;
                old_o = acto ? no : NEGV;
                bool hv = (t == fl - 1) && (t < TT);
                Esave = hv ? old_e : Esave;
                Osave = hv ? old_o : Osave;
            }
        }
        float a_last = __shfl(Esave, tl);
        float a_prev = __shfl(Osave, tl - 1);
        if (u == 0) loss_ctc[b] = -lae(a_last, a_prev);
    }
}

// ---------------- final combine -------------------------------------------
__global__ void combine(const float* __restrict__ lr, const float* __restrict__ lc,
                        float* __restrict__ out)
{
    float r = 0.25f * (lr[0] + lr[1] + lr[2] + lr[3]);
    float c = 0.25f * (lc[0] + lc[1] + lc[2] + lc[3]);
    out[0] = r + 0.3f * c;
}

extern "C" void kernel_launch(void* const* d_in, const int* in_sizes, int n_in,
                              void* d_out, int out_size, void* d_ws, size_t ws_size,
                              hipStream_t stream)
{
    const float* x_enc   = (const float*)d_in[0];
    const float* x_dec   = (const float*)d_in[1];
    const int*   target  = (const int*)d_in[2];
    const int*   frame_l = (const int*)d_in[3];
    const int*   tgt_l   = (const int*)d_in[4];
    const float* W_ctc   = (const float*)d_in[5];
    const float* b_ctc   = (const float*)d_in[6];
    const float* W_enc   = (const float*)d_in[7];
    const float* W_pred  = (const float*)d_in[8];
    const float* b_joint = (const float*)d_in[9];
    const float* W_out   = (const float*)d_in[10];
    const float* b_out   = (const float*)d_in[11];
    float* out = (float*)d_out;

    float* wsf        = (float*)d_ws;
    float* enc_proj   = wsf;                       // 512000
    float* pred_proj  = wsf + 512000;              // 130560
    float* ctc_logits = wsf + 642560;              // 819200
    float* ctc_lse    = wsf + 1461760;             // 832
    float* blank_buf  = wsf + 1462592;             // 40832
    float* emit_buf   = wsf + 1503424;             // 40832
    float* loss_rnnt  = wsf + 1544256;             // 4
    float* loss_ctc   = wsf + 1544260;             // 4 (+pad to 1544272)
    unsigned* FOut8 = (unsigned*)(wsf + 1544272);  // 163840 u32 (655360 B fp8)
    bf16_t* FEnc  = (bf16_t*)(wsf + 1708112);      // 327680 bf16
    bf16_t* FPred = (bf16_t*)(wsf + 1871952);      // 409600 bf16
    bf16_t* FCtc  = (bf16_t*)(wsf + 2076752);      // 524288 bf16

    pack_all<<<5568, 256, 0, stream>>>(W_out, W_enc, W_pred, W_ctc, FOut8, FEnc, FPred, FCtc);
    mfma_gemm3<<<30, 512, 0, stream>>>(x_enc, x_dec, FEnc, FPred, FCtc, b_ctc,
                                       enc_proj, pred_proj, ctc_logits, ctc_lse);
    joint_gemm<<<RPAD / 64, 512, 0, stream>>>(enc_proj, pred_proj, b_joint, FOut8, b_out,
                                              target, blank_buf, emit_buf);
    dp_fused<<<8, 256, 0, stream>>>(blank_buf, emit_buf, ctc_logits, ctc_lse,
                                    target, frame_l, tgt_l, loss_rnnt, loss_ctc);
    combine<<<1, 1, 0, stream>>>(loss_rnnt, loss_ctc, out);
}